// Round 1
// baseline (1802.065 us; speedup 1.0000x reference)
//
#include <hip/hip_runtime.h>
#include <math.h>

#define BSZ 2
#define LSEQ 1024
#define DM 1024
#define DI 2048
#define DS 16
#define MROWS (BSZ * LSEQ)   // 2048

// ---------- tiled fp32 GEMM: C[M,N] = A[M,K] * W[N,K]^T ----------
// EPI: 0 = none, 1 = +bias then softplus
template <int EPI>
__global__ void gemm_nt(const float* __restrict__ A, const float* __restrict__ W,
                        const float* __restrict__ bias, float* __restrict__ C,
                        int M, int N, int K) {
  __shared__ float As[16][65];
  __shared__ float Ws[16][65];
  int tid = threadIdx.x;
  int tx = tid & 15;        // n sub-tile
  int ty = tid >> 4;        // m sub-tile
  int m0 = blockIdx.y * 64;
  int n0 = blockIdx.x * 64;
  float acc[4][4] = {};
  for (int k0 = 0; k0 < K; k0 += 16) {
#pragma unroll
    for (int i = 0; i < 4; ++i) {
      int idx = tid + i * 256;
      int r = idx >> 4, c = idx & 15;
      As[c][r] = A[(size_t)(m0 + r) * K + (k0 + c)];
      Ws[c][r] = W[(size_t)(n0 + r) * K + (k0 + c)];
    }
    __syncthreads();
#pragma unroll
    for (int kk = 0; kk < 16; ++kk) {
      float a[4], w[4];
#pragma unroll
      for (int i = 0; i < 4; ++i) a[i] = As[kk][ty * 4 + i];
#pragma unroll
      for (int j = 0; j < 4; ++j) w[j] = Ws[kk][tx * 4 + j];
#pragma unroll
      for (int i = 0; i < 4; ++i)
#pragma unroll
        for (int j = 0; j < 4; ++j) acc[i][j] += a[i] * w[j];
    }
    __syncthreads();
  }
#pragma unroll
  for (int i = 0; i < 4; ++i) {
    int m = m0 + ty * 4 + i;
#pragma unroll
    for (int j = 0; j < 4; ++j) {
      int n = n0 + tx * 4 + j;
      float v = acc[i][j];
      if (EPI == 1) {
        v += bias[n];
        v = (v > 20.f) ? v : log1pf(expf(v));   // softplus
      }
      C[(size_t)m * N + n] = v;
    }
  }
}

// ---------- depthwise conv1d k=3 pad=1 + bias + silu ----------
__global__ void conv_silu(const float* __restrict__ xz, const float* __restrict__ cw,
                          const float* __restrict__ cb, float* __restrict__ xsc) {
  int idx = blockIdx.x * 256 + threadIdx.x;  // over B*L*DI
  if (idx >= BSZ * LSEQ * DI) return;
  int d = idx & (DI - 1);
  int bt = idx >> 11;           // row index (b*L + t)
  int t = bt & (LSEQ - 1);
  const float* base = xz + (size_t)bt * (2 * DI) + d;  // xs part: cols [0,DI)
  float acc = cb[d];
  float w0 = cw[d * 3 + 0], w1 = cw[d * 3 + 1], w2 = cw[d * 3 + 2];
  if (t > 0) acc += base[-(2 * DI)] * w0;
  acc += base[0] * w1;
  if (t < LSEQ - 1) acc += base[2 * DI] * w2;
  float s = acc / (1.f + expf(-acc));   // silu
  xsc[idx] = s;
}

// ---------- small GEMM: BC[M,32] = xsc[M,DI] * x_proj_w[32,DI]^T ----------
__global__ void gemm_bc(const float* __restrict__ A, const float* __restrict__ W,
                        float* __restrict__ C) {
  int tid = threadIdx.x;          // 256 threads: 32 n x 8 rows
  int n = tid & 31;
  int r = tid >> 5;
  int m = blockIdx.x * 8 + r;
  const float* a = A + (size_t)m * DI;
  const float* w = W + (size_t)n * DI;
  float acc = 0.f;
#pragma unroll 8
  for (int k = 0; k < DI; ++k) acc += a[k] * w[k];
  C[m * 32 + n] = acc;
}

// ---------- sequential selective scan ----------
// block: 256 threads = 16 channels x 16 states; grid: B * (DI/16) = 256
__global__ void scan_kernel(const float* __restrict__ delta,
                            const float* __restrict__ xsc,
                            const float* __restrict__ bc,
                            const float* __restrict__ xz,
                            const float* __restrict__ A_log,
                            const float* __restrict__ Dv,
                            float* __restrict__ hidden,
                            float* __restrict__ yout) {
  int tid = threadIdx.x;
  int n = tid & 15;
  int dl = tid >> 4;
  int b = blockIdx.x >> 7;
  int d = (blockIdx.x & 127) * 16 + dl;
  float Av = -expf(A_log[d * DS + n]);
  float Dd = Dv[d];
  float h = 0.f;
  size_t rowBase = (size_t)b * LSEQ;
  for (int t = 0; t < LSEQ; ++t) {
    size_t row = rowBase + t;
    float dlt = delta[row * DI + d];
    float xv = xsc[row * DI + d];
    float Bn = bc[row * 32 + n];
    float Cn = bc[row * 32 + 16 + n];
    float dA = expf(dlt * Av);
    h = dA * h + (dlt * xv) * Bn;
    hidden[(row * DI + d) * DS + n] = h;
    float p = h * Cn;
    p += __shfl_xor(p, 1, 16);
    p += __shfl_xor(p, 2, 16);
    p += __shfl_xor(p, 4, 16);
    p += __shfl_xor(p, 8, 16);
    if (n == 0) {
      float zv = xz[row * (2 * DI) + DI + d];
      float y = (p + xv * Dd) * (zv / (1.f + expf(-zv)));
      yout[row * DI + d] = y;
    }
  }
}

extern "C" void kernel_launch(void* const* d_in, const int* in_sizes, int n_in,
                              void* d_out, int out_size, void* d_ws, size_t ws_size,
                              hipStream_t stream) {
  const float* x         = (const float*)d_in[0];
  const float* in_proj_w = (const float*)d_in[1];
  const float* conv_w    = (const float*)d_in[2];
  const float* conv_b    = (const float*)d_in[3];
  const float* x_proj_w  = (const float*)d_in[4];
  const float* dt_proj_w = (const float*)d_in[5];
  const float* dt_proj_b = (const float*)d_in[6];
  const float* out_proj_w= (const float*)d_in[7];
  const float* A_log     = (const float*)d_in[8];
  const float* Dvec      = (const float*)d_in[9];

  float* out    = (float*)d_out;                       // (B,L,DM)
  float* hidden = (float*)d_out + (size_t)BSZ * LSEQ * DM;  // (B,L,DI,DS)

  float* ws  = (float*)d_ws;
  float* xz    = ws;                                   // (M, 2*DI) = 8M
  float* xsc   = xz  + (size_t)MROWS * 2 * DI;         // (M, DI)   = 4M
  float* delta = xsc + (size_t)MROWS * DI;             // (M, DI)   = 4M
  float* bcbuf = delta + (size_t)MROWS * DI;           // (M, 32)
  float* ybuf  = bcbuf + (size_t)MROWS * 32;           // (M, DI)   = 4M

  dim3 blk(256);

  // 1) xz = x @ in_proj_w^T   (M=2048, N=4096, K=1024)
  gemm_nt<0><<<dim3(4096 / 64, MROWS / 64), blk, 0, stream>>>(
      x, in_proj_w, nullptr, xz, MROWS, 2 * DI, DM);

  // 2) depthwise conv + silu -> xsc
  conv_silu<<<dim3((BSZ * LSEQ * DI) / 256), blk, 0, stream>>>(xz, conv_w, conv_b, xsc);

  // 3) delta = softplus(xsc @ dt_proj_w^T + b)   (M=2048, N=2048, K=2048)
  gemm_nt<1><<<dim3(DI / 64, MROWS / 64), blk, 0, stream>>>(
      xsc, dt_proj_w, dt_proj_b, delta, MROWS, DI, DI);

  // 4) BC = xsc @ x_proj_w^T   (N=32)
  gemm_bc<<<dim3(MROWS / 8), blk, 0, stream>>>(xsc, x_proj_w, bcbuf);

  // 5) selective scan -> hidden, ybuf
  scan_kernel<<<dim3(BSZ * (DI / 16)), blk, 0, stream>>>(
      delta, xsc, bcbuf, xz, A_log, Dvec, hidden, ybuf);

  // 6) out = ybuf @ out_proj_w^T   (M=2048, N=1024, K=2048)
  gemm_nt<0><<<dim3(DM / 64, MROWS / 64), blk, 0, stream>>>(
      ybuf, out_proj_w, nullptr, out, MROWS, DM, DI);
}

// Round 2
// 1151.617 us; speedup vs baseline: 1.5648x; 1.5648x over previous
//
#include <hip/hip_runtime.h>
#include <math.h>

#define BSZ 2
#define LSEQ 1024
#define DM 1024
#define DI 2048
#define DS 16
#define MROWS (BSZ * LSEQ)   // 2048
#define NC 64                // time chunks for parallel scan
#define CLEN (LSEQ / NC)     // 16

// ---------- tiled fp32 GEMM: C[M,N] = A[M,K] * W[N,K]^T ----------
// EPI: 0 = none, 1 = +bias then softplus
template <int EPI>
__global__ void gemm_nt(const float* __restrict__ A, const float* __restrict__ W,
                        const float* __restrict__ bias, float* __restrict__ C,
                        int M, int N, int K) {
  __shared__ float As[16][65];
  __shared__ float Ws[16][65];
  int tid = threadIdx.x;
  int tx = tid & 15;        // n sub-tile
  int ty = tid >> 4;        // m sub-tile
  int m0 = blockIdx.y * 64;
  int n0 = blockIdx.x * 64;
  float acc[4][4] = {};
  for (int k0 = 0; k0 < K; k0 += 16) {
#pragma unroll
    for (int i = 0; i < 4; ++i) {
      int idx = tid + i * 256;
      int r = idx >> 4, c = idx & 15;
      As[c][r] = A[(size_t)(m0 + r) * K + (k0 + c)];
      Ws[c][r] = W[(size_t)(n0 + r) * K + (k0 + c)];
    }
    __syncthreads();
#pragma unroll
    for (int kk = 0; kk < 16; ++kk) {
      float a[4], w[4];
#pragma unroll
      for (int i = 0; i < 4; ++i) a[i] = As[kk][ty * 4 + i];
#pragma unroll
      for (int j = 0; j < 4; ++j) w[j] = Ws[kk][tx * 4 + j];
#pragma unroll
      for (int i = 0; i < 4; ++i)
#pragma unroll
        for (int j = 0; j < 4; ++j) acc[i][j] += a[i] * w[j];
    }
    __syncthreads();
  }
#pragma unroll
  for (int i = 0; i < 4; ++i) {
    int m = m0 + ty * 4 + i;
#pragma unroll
    for (int j = 0; j < 4; ++j) {
      int n = n0 + tx * 4 + j;
      float v = acc[i][j];
      if (EPI == 1) {
        v += bias[n];
        v = (v > 20.f) ? v : log1pf(expf(v));   // softplus
      }
      C[(size_t)m * N + n] = v;
    }
  }
}

// ---------- depthwise conv1d k=3 pad=1 + bias + silu ----------
__global__ void conv_silu(const float* __restrict__ xz, const float* __restrict__ cw,
                          const float* __restrict__ cb, float* __restrict__ xsc) {
  int idx = blockIdx.x * 256 + threadIdx.x;  // over B*L*DI
  if (idx >= BSZ * LSEQ * DI) return;
  int d = idx & (DI - 1);
  int bt = idx >> 11;           // row index (b*L + t)
  int t = bt & (LSEQ - 1);
  const float* base = xz + (size_t)bt * (2 * DI) + d;  // xs part: cols [0,DI)
  float acc = cb[d];
  float w0 = cw[d * 3 + 0], w1 = cw[d * 3 + 1], w2 = cw[d * 3 + 2];
  if (t > 0) acc += base[-(2 * DI)] * w0;
  acc += base[0] * w1;
  if (t < LSEQ - 1) acc += base[2 * DI] * w2;
  float s = acc / (1.f + expf(-acc));   // silu
  xsc[idx] = s;
}

// ---------- small GEMM: BC[M,32] = xsc[M,DI] * x_proj_w[32,DI]^T ----------
__global__ void gemm_bc(const float* __restrict__ A, const float* __restrict__ W,
                        float* __restrict__ C) {
  int tid = threadIdx.x;          // 256 threads: 32 n x 8 rows
  int n = tid & 31;
  int r = tid >> 5;
  int m = blockIdx.x * 8 + r;
  const float* a = A + (size_t)m * DI;
  const float* w = W + (size_t)n * DI;
  float acc = 0.f;
#pragma unroll 8
  for (int k = 0; k < DI; ++k) acc += a[k] * w[k];
  C[m * 32 + n] = acc;
}

// ---------- chunked parallel scan ----------
// Phase A: per (b, d, chunk): local scan with h0 = 0, all DS states in regs.
// Writes chunk-final local state hloc and sum of delta over the chunk.
__global__ void scan_phaseA(const float* __restrict__ delta,
                            const float* __restrict__ xsc,
                            const float* __restrict__ bc,
                            const float* __restrict__ A_log,
                            float* __restrict__ hloc,
                            float* __restrict__ dsum) {
  int tid = threadIdx.x;
  int d = blockIdx.x * 256 + tid;
  int c = blockIdx.y;
  int b = blockIdx.z;
  float Av[DS];
#pragma unroll
  for (int n = 0; n < DS; n += 4) {
    float4 v = *(const float4*)(A_log + d * DS + n);
    Av[n] = -__expf(v.x); Av[n+1] = -__expf(v.y);
    Av[n+2] = -__expf(v.z); Av[n+3] = -__expf(v.w);
  }
  float h[DS] = {};
  float sd = 0.f;
  size_t row = (size_t)b * LSEQ + (size_t)c * CLEN;
  for (int t = 0; t < CLEN; ++t, ++row) {
    float dlt = delta[row * DI + d];
    float xv  = xsc[row * DI + d];
    float dx = dlt * xv;
    sd += dlt;
#pragma unroll
    for (int n = 0; n < DS; ++n) {
      float Bn = bc[row * 32 + n];
      float dA = __expf(dlt * Av[n]);
      h[n] = dA * h[n] + dx * Bn;
    }
  }
  size_t o = ((size_t)(b * NC + c) * DI + d) * DS;
#pragma unroll
  for (int n = 0; n < DS; n += 4)
    *(float4*)(hloc + o + n) = make_float4(h[n], h[n+1], h[n+2], h[n+3]);
  dsum[(b * NC + c) * DI + d] = sd;
}

// Phase B: per (b, d, n): serial prefix over chunk summaries -> hin per chunk.
// Product of dA over a chunk = exp(Av * sum(delta)).
__global__ void scan_phaseB(const float* __restrict__ hloc,
                            const float* __restrict__ dsum,
                            const float* __restrict__ A_log,
                            float* __restrict__ hin) {
  int gid = blockIdx.x * 256 + threadIdx.x;   // over B*DI*DS
  int n = gid & 15;
  int d = (gid >> 4) & (DI - 1);
  int b = gid >> 15;
  float Av = -__expf(A_log[d * DS + n]);
  float h = 0.f;
  for (int c = 0; c < NC; ++c) {
    size_t o = ((size_t)(b * NC + c) * DI + d) * DS + n;
    hin[o] = h;
    float p = __expf(Av * dsum[(b * NC + c) * DI + d]);
    h = hloc[o] + p * h;
  }
}

// Phase C: full scan within each chunk seeded with hin; writes hidden and
// fused y = (sum_n h*C + x*D) * silu(z).
__global__ void scan_phaseC(const float* __restrict__ delta,
                            const float* __restrict__ xsc,
                            const float* __restrict__ bc,
                            const float* __restrict__ xz,
                            const float* __restrict__ A_log,
                            const float* __restrict__ Dv,
                            const float* __restrict__ hin,
                            float* __restrict__ hidden,
                            float* __restrict__ yout) {
  int tid = threadIdx.x;
  int d = blockIdx.x * 256 + tid;
  int c = blockIdx.y;
  int b = blockIdx.z;
  float Av[DS];
#pragma unroll
  for (int n = 0; n < DS; n += 4) {
    float4 v = *(const float4*)(A_log + d * DS + n);
    Av[n] = -__expf(v.x); Av[n+1] = -__expf(v.y);
    Av[n+2] = -__expf(v.z); Av[n+3] = -__expf(v.w);
  }
  float Dd = Dv[d];
  float h[DS];
  size_t so = ((size_t)(b * NC + c) * DI + d) * DS;
#pragma unroll
  for (int n = 0; n < DS; n += 4) {
    float4 v = *(const float4*)(hin + so + n);
    h[n] = v.x; h[n+1] = v.y; h[n+2] = v.z; h[n+3] = v.w;
  }
  size_t row = (size_t)b * LSEQ + (size_t)c * CLEN;
  for (int t = 0; t < CLEN; ++t, ++row) {
    float dlt = delta[row * DI + d];
    float xv  = xsc[row * DI + d];
    float dx = dlt * xv;
    float y = 0.f;
#pragma unroll
    for (int n = 0; n < DS; ++n) {
      float Bn = bc[row * 32 + n];
      float Cn = bc[row * 32 + 16 + n];
      float dA = __expf(dlt * Av[n]);
      h[n] = dA * h[n] + dx * Bn;
      y += h[n] * Cn;
    }
    size_t ho = (row * DI + d) * DS;
#pragma unroll
    for (int n = 0; n < DS; n += 4)
      *(float4*)(hidden + ho + n) = make_float4(h[n], h[n+1], h[n+2], h[n+3]);
    float zv = xz[row * (2 * DI) + DI + d];
    float sz = zv / (1.f + __expf(-zv));
    yout[row * DI + d] = (y + xv * Dd) * sz;
  }
}

extern "C" void kernel_launch(void* const* d_in, const int* in_sizes, int n_in,
                              void* d_out, int out_size, void* d_ws, size_t ws_size,
                              hipStream_t stream) {
  const float* x         = (const float*)d_in[0];
  const float* in_proj_w = (const float*)d_in[1];
  const float* conv_w    = (const float*)d_in[2];
  const float* conv_b    = (const float*)d_in[3];
  const float* x_proj_w  = (const float*)d_in[4];
  const float* dt_proj_w = (const float*)d_in[5];
  const float* dt_proj_b = (const float*)d_in[6];
  const float* out_proj_w= (const float*)d_in[7];
  const float* A_log     = (const float*)d_in[8];
  const float* Dvec      = (const float*)d_in[9];

  float* out    = (float*)d_out;                            // (B,L,DM)
  float* hidden = (float*)d_out + (size_t)BSZ * LSEQ * DM;  // (B,L,DI,DS)

  float* ws  = (float*)d_ws;
  float* xz    = ws;                                   // (M, 2*DI)  8M floats
  float* xsc   = xz  + (size_t)MROWS * 2 * DI;         // (M, DI)    4M
  float* delta = xsc + (size_t)MROWS * DI;             // (M, DI)    4M
  float* bcbuf = delta + (size_t)MROWS * DI;           // (M, 32)
  float* ybuf  = bcbuf + (size_t)MROWS * 32;           // (M, DI)    4M
  float* hloc  = ybuf + (size_t)MROWS * DI;            // (B,NC,DI,DS) 4M
  float* hin   = hloc + (size_t)BSZ * NC * DI * DS;    // (B,NC,DI,DS) 4M
  float* dsum  = hin  + (size_t)BSZ * NC * DI * DS;    // (B,NC,DI)  256K

  dim3 blk(256);

  // 1) xz = x @ in_proj_w^T   (M=2048, N=4096, K=1024)
  gemm_nt<0><<<dim3(4096 / 64, MROWS / 64), blk, 0, stream>>>(
      x, in_proj_w, nullptr, xz, MROWS, 2 * DI, DM);

  // 2) depthwise conv + silu -> xsc
  conv_silu<<<dim3((BSZ * LSEQ * DI) / 256), blk, 0, stream>>>(xz, conv_w, conv_b, xsc);

  // 3) delta = softplus(xsc @ dt_proj_w^T + b)   (M=2048, N=2048, K=2048)
  gemm_nt<1><<<dim3(DI / 64, MROWS / 64), blk, 0, stream>>>(
      xsc, dt_proj_w, dt_proj_b, delta, MROWS, DI, DI);

  // 4) BC = xsc @ x_proj_w^T   (N=32)
  gemm_bc<<<dim3(MROWS / 8), blk, 0, stream>>>(xsc, x_proj_w, bcbuf);

  // 5) chunked parallel scan -> hidden, ybuf
  scan_phaseA<<<dim3(DI / 256, NC, BSZ), blk, 0, stream>>>(
      delta, xsc, bcbuf, A_log, hloc, dsum);
  scan_phaseB<<<dim3((BSZ * DI * DS) / 256), blk, 0, stream>>>(
      hloc, dsum, A_log, hin);
  scan_phaseC<<<dim3(DI / 256, NC, BSZ), blk, 0, stream>>>(
      delta, xsc, bcbuf, xz, A_log, Dvec, hin, hidden, ybuf);

  // 6) out = ybuf @ out_proj_w^T   (M=2048, N=1024, K=2048)
  gemm_nt<0><<<dim3(DM / 64, MROWS / 64), blk, 0, stream>>>(
      ybuf, out_proj_w, nullptr, out, MROWS, DM, DI);
}

// Round 3
// 571.568 us; speedup vs baseline: 3.1528x; 2.0148x over previous
//
#include <hip/hip_runtime.h>
#include <math.h>

#define BSZ 2
#define LSEQ 1024
#define DM 1024
#define DI 2048
#define DS 16
#define MROWS (BSZ * LSEQ)   // 2048
#define NC 64                // time chunks for parallel scan
#define CLEN (LSEQ / NC)     // 16

typedef __attribute__((ext_vector_type(8))) short short8;
typedef __attribute__((ext_vector_type(4))) float f32x4;

__device__ inline unsigned short bf16_rn(float f) {
  unsigned u = __builtin_bit_cast(unsigned, f);
  u = (u + 0x7FFFu + ((u >> 16) & 1u)) >> 16;
  return (unsigned short)u;
}
__device__ inline float bf16_f32(unsigned short h) {
  unsigned u = ((unsigned)h) << 16;
  return __builtin_bit_cast(float, u);
}

// load 8 fp32, split into hi/lo bf16, store as two short8 to LDS
__device__ inline void split8(const float* __restrict__ g,
                              unsigned short* __restrict__ hd,
                              unsigned short* __restrict__ ld) {
  f32x4 t0 = *(const f32x4*)g;
  f32x4 t1 = *(const f32x4*)(g + 4);
  short8 h, l;
#pragma unroll
  for (int j = 0; j < 4; ++j) {
    float x = t0[j];
    unsigned short hb = bf16_rn(x);
    h[j] = (short)hb;
    l[j] = (short)bf16_rn(x - bf16_f32(hb));
  }
#pragma unroll
  for (int j = 0; j < 4; ++j) {
    float x = t1[j];
    unsigned short hb = bf16_rn(x);
    h[4 + j] = (short)hb;
    l[4 + j] = (short)bf16_rn(x - bf16_f32(hb));
  }
  *(short8*)hd = h;
  *(short8*)ld = l;
}

// ---------- bf16-split MFMA GEMM: C[M,N] = A[M,K] * W[N,K]^T ----------
// EPI: 0 = none, 1 = +bias then softplus
#define BM 128
#define BN 128
#define BK 32
#define LDT 40   // LDS row stride in bf16 elems (80B; slot stride 5 mod 8)

template <int EPI>
__global__ __launch_bounds__(256, 2) void gemm_mfma(
    const float* __restrict__ A, const float* __restrict__ W,
    const float* __restrict__ bias, float* __restrict__ C,
    int M, int N, int K) {
  __shared__ unsigned short Ah[BM * LDT], Al[BM * LDT];
  __shared__ unsigned short Wh[BN * LDT], Wl[BN * LDT];
  int tid = threadIdx.x;
  int m0 = blockIdx.y * BM, n0 = blockIdx.x * BN;
  int lane = tid & 63, wid = tid >> 6;
  int wm = (wid >> 1) * 64, wn = (wid & 1) * 64;
  int fr = lane & 15, fq = lane >> 4;
  int srow = tid >> 1, shalf = tid & 1;   // staging: row, 16-col half

  f32x4 acc[4][4];
#pragma unroll
  for (int i = 0; i < 4; ++i)
#pragma unroll
    for (int j = 0; j < 4; ++j) acc[i][j] = (f32x4){0.f, 0.f, 0.f, 0.f};

  const float* pa = A + (size_t)(m0 + srow) * K + shalf * 16;
  const float* pw = W + (size_t)(n0 + srow) * K + shalf * 16;
  int soff = srow * LDT + shalf * 16;

  for (int k0 = 0; k0 < K; k0 += BK) {
    split8(pa + k0,     &Ah[soff],     &Al[soff]);
    split8(pa + k0 + 8, &Ah[soff + 8], &Al[soff + 8]);
    split8(pw + k0,     &Wh[soff],     &Wl[soff]);
    split8(pw + k0 + 8, &Wh[soff + 8], &Wl[soff + 8]);
    __syncthreads();

    short8 ah[4], al[4], wh[4], wl[4];
#pragma unroll
    for (int f = 0; f < 4; ++f) {
      int ra = (wm + f * 16 + fr) * LDT + fq * 8;
      ah[f] = *(const short8*)&Ah[ra];
      al[f] = *(const short8*)&Al[ra];
      int rw = (wn + f * 16 + fr) * LDT + fq * 8;
      wh[f] = *(const short8*)&Wh[rw];
      wl[f] = *(const short8*)&Wl[rw];
    }
#pragma unroll
    for (int i = 0; i < 4; ++i)
#pragma unroll
      for (int j = 0; j < 4; ++j) {
        acc[i][j] = __builtin_amdgcn_mfma_f32_16x16x32_bf16(ah[i], wh[j], acc[i][j], 0, 0, 0);
        acc[i][j] = __builtin_amdgcn_mfma_f32_16x16x32_bf16(ah[i], wl[j], acc[i][j], 0, 0, 0);
        acc[i][j] = __builtin_amdgcn_mfma_f32_16x16x32_bf16(al[i], wh[j], acc[i][j], 0, 0, 0);
      }
    __syncthreads();
  }

#pragma unroll
  for (int i = 0; i < 4; ++i) {
    int m = m0 + wm + i * 16 + fq * 4;
#pragma unroll
    for (int j = 0; j < 4; ++j) {
      int n = n0 + wn + j * 16 + fr;
#pragma unroll
      for (int r = 0; r < 4; ++r) {
        float v = acc[i][j][r];
        if (EPI == 1) {
          v += bias[n];
          v = (v > 20.f) ? v : log1pf(expf(v));   // softplus
        }
        C[(size_t)(m + r) * N + n] = v;
      }
    }
  }
}

// ---------- depthwise conv1d k=3 pad=1 + bias + silu ----------
__global__ void conv_silu(const float* __restrict__ xz, const float* __restrict__ cw,
                          const float* __restrict__ cb, float* __restrict__ xsc) {
  int idx = blockIdx.x * 256 + threadIdx.x;  // over B*L*DI
  if (idx >= BSZ * LSEQ * DI) return;
  int d = idx & (DI - 1);
  int bt = idx >> 11;           // row index (b*L + t)
  int t = bt & (LSEQ - 1);
  const float* base = xz + (size_t)bt * (2 * DI) + d;  // xs part: cols [0,DI)
  float acc = cb[d];
  float w0 = cw[d * 3 + 0], w1 = cw[d * 3 + 1], w2 = cw[d * 3 + 2];
  if (t > 0) acc += base[-(2 * DI)] * w0;
  acc += base[0] * w1;
  if (t < LSEQ - 1) acc += base[2 * DI] * w2;
  float s = acc / (1.f + expf(-acc));   // silu
  xsc[idx] = s;
}

// ---------- small GEMM: BC[M,32] = xsc[M,DI] * x_proj_w[32,DI]^T ----------
__global__ void gemm_bc(const float* __restrict__ A, const float* __restrict__ W,
                        float* __restrict__ C) {
  int tid = threadIdx.x;          // 256 threads: 32 n x 8 rows
  int n = tid & 31;
  int r = tid >> 5;
  int m = blockIdx.x * 8 + r;
  const f32x4* a = (const f32x4*)(A + (size_t)m * DI);
  const f32x4* w = (const f32x4*)(W + (size_t)n * DI);
  float acc = 0.f;
#pragma unroll 4
  for (int k = 0; k < DI / 4; ++k) {
    f32x4 av = a[k], wv = w[k];
    acc += av[0] * wv[0] + av[1] * wv[1] + av[2] * wv[2] + av[3] * wv[3];
  }
  C[m * 32 + n] = acc;
}

// ---------- chunked parallel scan ----------
__global__ void scan_phaseA(const float* __restrict__ delta,
                            const float* __restrict__ xsc,
                            const float* __restrict__ bc,
                            const float* __restrict__ A_log,
                            float* __restrict__ hloc,
                            float* __restrict__ dsum) {
  int tid = threadIdx.x;
  int d = blockIdx.x * 256 + tid;
  int c = blockIdx.y;
  int b = blockIdx.z;
  float Av[DS];
#pragma unroll
  for (int n = 0; n < DS; n += 4) {
    float4 v = *(const float4*)(A_log + d * DS + n);
    Av[n] = -__expf(v.x); Av[n+1] = -__expf(v.y);
    Av[n+2] = -__expf(v.z); Av[n+3] = -__expf(v.w);
  }
  float h[DS] = {};
  float sd = 0.f;
  size_t row = (size_t)b * LSEQ + (size_t)c * CLEN;
  for (int t = 0; t < CLEN; ++t, ++row) {
    float dlt = delta[row * DI + d];
    float xv  = xsc[row * DI + d];
    float dx = dlt * xv;
    sd += dlt;
#pragma unroll
    for (int n = 0; n < DS; ++n) {
      float Bn = bc[row * 32 + n];
      float dA = __expf(dlt * Av[n]);
      h[n] = dA * h[n] + dx * Bn;
    }
  }
  size_t o = ((size_t)(b * NC + c) * DI + d) * DS;
#pragma unroll
  for (int n = 0; n < DS; n += 4)
    *(float4*)(hloc + o + n) = make_float4(h[n], h[n+1], h[n+2], h[n+3]);
  dsum[(b * NC + c) * DI + d] = sd;
}

__global__ void scan_phaseB(const float* __restrict__ hloc,
                            const float* __restrict__ dsum,
                            const float* __restrict__ A_log,
                            float* __restrict__ hin) {
  int gid = blockIdx.x * 256 + threadIdx.x;   // over B*DI*DS
  int n = gid & 15;
  int d = (gid >> 4) & (DI - 1);
  int b = gid >> 15;
  float Av = -__expf(A_log[d * DS + n]);
  float h = 0.f;
  for (int c = 0; c < NC; ++c) {
    size_t o = ((size_t)(b * NC + c) * DI + d) * DS + n;
    hin[o] = h;
    float p = __expf(Av * dsum[(b * NC + c) * DI + d]);
    h = hloc[o] + p * h;
  }
}

__global__ void scan_phaseC(const float* __restrict__ delta,
                            const float* __restrict__ xsc,
                            const float* __restrict__ bc,
                            const float* __restrict__ xz,
                            const float* __restrict__ A_log,
                            const float* __restrict__ Dv,
                            const float* __restrict__ hin,
                            float* __restrict__ hidden,
                            float* __restrict__ yout) {
  int tid = threadIdx.x;
  int d = blockIdx.x * 256 + tid;
  int c = blockIdx.y;
  int b = blockIdx.z;
  float Av[DS];
#pragma unroll
  for (int n = 0; n < DS; n += 4) {
    float4 v = *(const float4*)(A_log + d * DS + n);
    Av[n] = -__expf(v.x); Av[n+1] = -__expf(v.y);
    Av[n+2] = -__expf(v.z); Av[n+3] = -__expf(v.w);
  }
  float Dd = Dv[d];
  float h[DS];
  size_t so = ((size_t)(b * NC + c) * DI + d) * DS;
#pragma unroll
  for (int n = 0; n < DS; n += 4) {
    float4 v = *(const float4*)(hin + so + n);
    h[n] = v.x; h[n+1] = v.y; h[n+2] = v.z; h[n+3] = v.w;
  }
  size_t row = (size_t)b * LSEQ + (size_t)c * CLEN;
  for (int t = 0; t < CLEN; ++t, ++row) {
    float dlt = delta[row * DI + d];
    float xv  = xsc[row * DI + d];
    float dx = dlt * xv;
    float y = 0.f;
#pragma unroll
    for (int n = 0; n < DS; ++n) {
      float Bn = bc[row * 32 + n];
      float Cn = bc[row * 32 + 16 + n];
      float dA = __expf(dlt * Av[n]);
      h[n] = dA * h[n] + dx * Bn;
      y += h[n] * Cn;
    }
    size_t ho = (row * DI + d) * DS;
#pragma unroll
    for (int n = 0; n < DS; n += 4)
      *(float4*)(hidden + ho + n) = make_float4(h[n], h[n+1], h[n+2], h[n+3]);
    float zv = xz[row * (2 * DI) + DI + d];
    float sz = zv / (1.f + __expf(-zv));
    yout[row * DI + d] = (y + xv * Dd) * sz;
  }
}

extern "C" void kernel_launch(void* const* d_in, const int* in_sizes, int n_in,
                              void* d_out, int out_size, void* d_ws, size_t ws_size,
                              hipStream_t stream) {
  const float* x         = (const float*)d_in[0];
  const float* in_proj_w = (const float*)d_in[1];
  const float* conv_w    = (const float*)d_in[2];
  const float* conv_b    = (const float*)d_in[3];
  const float* x_proj_w  = (const float*)d_in[4];
  const float* dt_proj_w = (const float*)d_in[5];
  const float* dt_proj_b = (const float*)d_in[6];
  const float* out_proj_w= (const float*)d_in[7];
  const float* A_log     = (const float*)d_in[8];
  const float* Dvec      = (const float*)d_in[9];

  float* out    = (float*)d_out;                            // (B,L,DM)
  float* hidden = (float*)d_out + (size_t)BSZ * LSEQ * DM;  // (B,L,DI,DS)

  float* ws  = (float*)d_ws;
  float* xz    = ws;                                   // (M, 2*DI)  8M floats
  float* xsc   = xz  + (size_t)MROWS * 2 * DI;         // (M, DI)    4M
  float* delta = xsc + (size_t)MROWS * DI;             // (M, DI)    4M
  float* bcbuf = delta + (size_t)MROWS * DI;           // (M, 32)
  float* ybuf  = bcbuf + (size_t)MROWS * 32;           // (M, DI)    4M
  float* hloc  = ybuf + (size_t)MROWS * DI;            // (B,NC,DI,DS) 4M
  float* hin   = hloc + (size_t)BSZ * NC * DI * DS;    // (B,NC,DI,DS) 4M
  float* dsum  = hin  + (size_t)BSZ * NC * DI * DS;    // (B,NC,DI)  256K

  dim3 blk(256);

  // 1) xz = x @ in_proj_w^T   (M=2048, N=4096, K=1024)
  gemm_mfma<0><<<dim3((2 * DI) / BN, MROWS / BM), blk, 0, stream>>>(
      x, in_proj_w, nullptr, xz, MROWS, 2 * DI, DM);

  // 2) depthwise conv + silu -> xsc
  conv_silu<<<dim3((BSZ * LSEQ * DI) / 256), blk, 0, stream>>>(xz, conv_w, conv_b, xsc);

  // 3) delta = softplus(xsc @ dt_proj_w^T + b)   (M=2048, N=2048, K=2048)
  gemm_mfma<1><<<dim3(DI / BN, MROWS / BM), blk, 0, stream>>>(
      xsc, dt_proj_w, dt_proj_b, delta, MROWS, DI, DI);

  // 4) BC = xsc @ x_proj_w^T   (N=32)
  gemm_bc<<<dim3(MROWS / 8), blk, 0, stream>>>(xsc, x_proj_w, bcbuf);

  // 5) chunked parallel scan -> hidden, ybuf
  scan_phaseA<<<dim3(DI / 256, NC, BSZ), blk, 0, stream>>>(
      delta, xsc, bcbuf, A_log, hloc, dsum);
  scan_phaseB<<<dim3((BSZ * DI * DS) / 256), blk, 0, stream>>>(
      hloc, dsum, A_log, hin);
  scan_phaseC<<<dim3(DI / 256, NC, BSZ), blk, 0, stream>>>(
      delta, xsc, bcbuf, xz, A_log, Dvec, hin, hidden, ybuf);

  // 6) out = ybuf @ out_proj_w^T   (M=2048, N=1024, K=2048)
  gemm_mfma<0><<<dim3(DM / BN, MROWS / BM), blk, 0, stream>>>(
      ybuf, out_proj_w, nullptr, out, MROWS, DM, DI);
}

// Round 4
// 497.069 us; speedup vs baseline: 3.6254x; 1.1499x over previous
//
#include <hip/hip_runtime.h>
#include <math.h>

#define BSZ 2
#define LSEQ 1024
#define DM 1024
#define DI 2048
#define DS 16
#define MROWS (BSZ * LSEQ)   // 2048
#define NC 64                // time chunks for parallel scan
#define CLEN (LSEQ / NC)     // 16
#define BK 32                // GEMM K-step

typedef __attribute__((ext_vector_type(8))) short short8;
typedef __attribute__((ext_vector_type(4))) float f32x4;
typedef unsigned short ushort_t;

__device__ inline ushort_t bf16_rn(float f) {
  unsigned u = __builtin_bit_cast(unsigned, f);
  u = (u + 0x7FFFu + ((u >> 16) & 1u)) >> 16;
  return (ushort_t)u;
}
__device__ inline float bf16_f32(ushort_t h) {
  unsigned u = ((unsigned)h) << 16;
  return __builtin_bit_cast(float, u);
}

// async global->LDS, 16 bytes per lane; lds base must be wave-uniform
__device__ inline void gload16(const void* g, void* l) {
  __builtin_amdgcn_global_load_lds(
      (const __attribute__((address_space(1))) unsigned*)g,
      (__attribute__((address_space(3))) unsigned*)l, 16, 0, 0);
}

// ---------- fp32 -> (bf16 hi, bf16 lo) pre-split ----------
__global__ void split_f32(const float* __restrict__ in, ushort_t* __restrict__ hi,
                          ushort_t* __restrict__ lo) {
  int i = (blockIdx.x * 256 + threadIdx.x) * 8;
  f32x4 a = *(const f32x4*)(in + i);
  f32x4 b = *(const f32x4*)(in + i + 4);
  short8 h, l;
#pragma unroll
  for (int j = 0; j < 4; ++j) {
    ushort_t hb = bf16_rn(a[j]);
    h[j] = (short)hb; l[j] = (short)bf16_rn(a[j] - bf16_f32(hb));
  }
#pragma unroll
  for (int j = 0; j < 4; ++j) {
    ushort_t hb = bf16_rn(b[j]);
    h[4 + j] = (short)hb; l[4 + j] = (short)bf16_rn(b[j] - bf16_f32(hb));
  }
  *(short8*)(hi + i) = h;
  *(short8*)(lo + i) = l;
}

// ---------- bf16-split MFMA GEMM: C[M,N] = A[M,K] * W[N,K]^T ----------
// A,W pre-split into hi/lo bf16. EPI: 0 = none, 1 = +bias softplus
template <int TM, int TN, int EPI>
__global__ __launch_bounds__(256) void gemm_mfma(
    const ushort_t* __restrict__ Ahg, const ushort_t* __restrict__ Alg,
    const ushort_t* __restrict__ Whg, const ushort_t* __restrict__ Wlg,
    const float* __restrict__ bias, float* __restrict__ C, int M, int N, int K) {
  constexpr int FI = TM / 32, FJ = TN / 32;
  __shared__ ushort_t Ah[TM * BK], Al[TM * BK], Wh[TN * BK], Wl[TN * BK];
  int tid = threadIdx.x, lane = tid & 63, wid = tid >> 6;
  int m0 = blockIdx.y * TM, n0 = blockIdx.x * TN;
  int wm = (wid >> 1) * (TM / 2), wn = (wid & 1) * (TN / 2);
  int fr = lane & 15, fq = lane >> 4;

  f32x4 acc[FI][FJ];
#pragma unroll
  for (int i = 0; i < FI; ++i)
#pragma unroll
    for (int j = 0; j < FJ; ++j) acc[i][j] = (f32x4){0.f, 0.f, 0.f, 0.f};

  for (int k0 = 0; k0 < K; k0 += BK) {
    // stage A (hi,lo): TM/64 issues of 4KB each
#pragma unroll
    for (int q = 0; q < TM / 64; ++q) {
      int i = q * 256 + wid * 64 + lane;
      int row = i >> 2, col = (i & 3) * 8;
      size_t go = (size_t)(m0 + row) * K + k0 + col;
      int lo8 = (q * 256 + wid * 64) * 8;       // wave-uniform LDS elem offset
      gload16(Ahg + go, &Ah[lo8]);
      gload16(Alg + go, &Al[lo8]);
    }
#pragma unroll
    for (int q = 0; q < TN / 64; ++q) {
      int i = q * 256 + wid * 64 + lane;
      int row = i >> 2, col = (i & 3) * 8;
      size_t go = (size_t)(n0 + row) * K + k0 + col;
      int lo8 = (q * 256 + wid * 64) * 8;
      gload16(Whg + go, &Wh[lo8]);
      gload16(Wlg + go, &Wl[lo8]);
    }
    __syncthreads();

    short8 ah[FI], al[FI], wh[FJ], wl[FJ];
#pragma unroll
    for (int f = 0; f < FI; ++f) {
      int ra = (wm + f * 16 + fr) * BK + fq * 8;
      ah[f] = *(const short8*)&Ah[ra];
      al[f] = *(const short8*)&Al[ra];
    }
#pragma unroll
    for (int f = 0; f < FJ; ++f) {
      int rw = (wn + f * 16 + fr) * BK + fq * 8;
      wh[f] = *(const short8*)&Wh[rw];
      wl[f] = *(const short8*)&Wl[rw];
    }
#pragma unroll
    for (int i = 0; i < FI; ++i)
#pragma unroll
      for (int j = 0; j < FJ; ++j) {
        acc[i][j] = __builtin_amdgcn_mfma_f32_16x16x32_bf16(ah[i], wh[j], acc[i][j], 0, 0, 0);
        acc[i][j] = __builtin_amdgcn_mfma_f32_16x16x32_bf16(ah[i], wl[j], acc[i][j], 0, 0, 0);
        acc[i][j] = __builtin_amdgcn_mfma_f32_16x16x32_bf16(al[i], wh[j], acc[i][j], 0, 0, 0);
      }
    __syncthreads();
  }

#pragma unroll
  for (int i = 0; i < FI; ++i) {
    int m = m0 + wm + i * 16 + fq * 4;
#pragma unroll
    for (int j = 0; j < FJ; ++j) {
      int n = n0 + wn + j * 16 + fr;
#pragma unroll
      for (int r = 0; r < 4; ++r) {
        float v = acc[i][j][r];
        if (EPI == 1) {
          v += bias[n];
          v = (v > 20.f) ? v : log1pf(expf(v));   // softplus
        }
        C[(size_t)(m + r) * N + n] = v;
      }
    }
  }
}

// ---------- depthwise conv1d k=3 pad=1 + bias + silu; fused bf16 split ----------
__global__ void conv_silu(const float* __restrict__ xz, const float* __restrict__ cw,
                          const float* __restrict__ cb, float* __restrict__ xsc,
                          ushort_t* __restrict__ xsch, ushort_t* __restrict__ xscl) {
  int idx = blockIdx.x * 256 + threadIdx.x;  // over B*L*DI
  int d = idx & (DI - 1);
  int bt = idx >> 11;           // row index (b*L + t)
  int t = bt & (LSEQ - 1);
  const float* base = xz + (size_t)bt * (2 * DI) + d;  // xs part: cols [0,DI)
  float acc = cb[d];
  float w0 = cw[d * 3 + 0], w1 = cw[d * 3 + 1], w2 = cw[d * 3 + 2];
  if (t > 0) acc += base[-(2 * DI)] * w0;
  acc += base[0] * w1;
  if (t < LSEQ - 1) acc += base[2 * DI] * w2;
  float s = acc / (1.f + __expf(-acc));   // silu
  xsc[idx] = s;
  ushort_t hb = bf16_rn(s);
  xsch[idx] = hb;
  xscl[idx] = bf16_rn(s - bf16_f32(hb));
}

// ---------- small GEMM: BC[M,32] = xsc[M,DI] * x_proj_w[32,DI]^T ----------
__global__ void gemm_bc(const float* __restrict__ A, const float* __restrict__ W,
                        float* __restrict__ C) {
  int tid = threadIdx.x;          // 256 threads: 32 n x 8 rows
  int n = tid & 31;
  int r = tid >> 5;
  int m = blockIdx.x * 8 + r;
  const f32x4* a = (const f32x4*)(A + (size_t)m * DI);
  const f32x4* w = (const f32x4*)(W + (size_t)n * DI);
  float acc = 0.f;
#pragma unroll 4
  for (int k = 0; k < DI / 4; ++k) {
    f32x4 av = a[k], wv = w[k];
    acc += av[0] * wv[0] + av[1] * wv[1] + av[2] * wv[2] + av[3] * wv[3];
  }
  C[m * 32 + n] = acc;
}

// ---------- chunked parallel scan ----------
__global__ void scan_phaseA(const float* __restrict__ delta,
                            const float* __restrict__ xsc,
                            const float* __restrict__ bc,
                            const float* __restrict__ A_log,
                            float* __restrict__ hloc,
                            float* __restrict__ dsum) {
  int tid = threadIdx.x;
  int d = blockIdx.x * 256 + tid;
  int c = blockIdx.y;
  int b = blockIdx.z;
  float Av[DS];
#pragma unroll
  for (int n = 0; n < DS; n += 4) {
    float4 v = *(const float4*)(A_log + d * DS + n);
    Av[n] = -__expf(v.x); Av[n+1] = -__expf(v.y);
    Av[n+2] = -__expf(v.z); Av[n+3] = -__expf(v.w);
  }
  float h[DS] = {};
  float sd = 0.f;
  size_t row = (size_t)b * LSEQ + (size_t)c * CLEN;
  for (int t = 0; t < CLEN; ++t, ++row) {
    float dlt = delta[row * DI + d];
    float xv  = xsc[row * DI + d];
    float dx = dlt * xv;
    sd += dlt;
#pragma unroll
    for (int n = 0; n < DS; ++n) {
      float Bn = bc[row * 32 + n];
      float dA = __expf(dlt * Av[n]);
      h[n] = dA * h[n] + dx * Bn;
    }
  }
  size_t o = ((size_t)(b * NC + c) * DI + d) * DS;
#pragma unroll
  for (int n = 0; n < DS; n += 4)
    *(float4*)(hloc + o + n) = make_float4(h[n], h[n+1], h[n+2], h[n+3]);
  dsum[(b * NC + c) * DI + d] = sd;
}

__global__ void scan_phaseB(const float* __restrict__ hloc,
                            const float* __restrict__ dsum,
                            const float* __restrict__ A_log,
                            float* __restrict__ hin) {
  int gid = blockIdx.x * 256 + threadIdx.x;   // over B*DI*DS
  int n = gid & 15;
  int d = (gid >> 4) & (DI - 1);
  int b = gid >> 15;
  float Av = -__expf(A_log[d * DS + n]);
  float h = 0.f;
  for (int c = 0; c < NC; ++c) {
    size_t o = ((size_t)(b * NC + c) * DI + d) * DS + n;
    hin[o] = h;
    float p = __expf(Av * dsum[(b * NC + c) * DI + d]);
    h = hloc[o] + p * h;
  }
}

__global__ void scan_phaseC(const float* __restrict__ delta,
                            const float* __restrict__ xsc,
                            const float* __restrict__ bc,
                            const float* __restrict__ xz,
                            const float* __restrict__ A_log,
                            const float* __restrict__ Dv,
                            const float* __restrict__ hin,
                            float* __restrict__ hidden,
                            ushort_t* __restrict__ yh,
                            ushort_t* __restrict__ yl) {
  int tid = threadIdx.x;
  int d = blockIdx.x * 256 + tid;
  int c = blockIdx.y;
  int b = blockIdx.z;
  float Av[DS];
#pragma unroll
  for (int n = 0; n < DS; n += 4) {
    float4 v = *(const float4*)(A_log + d * DS + n);
    Av[n] = -__expf(v.x); Av[n+1] = -__expf(v.y);
    Av[n+2] = -__expf(v.z); Av[n+3] = -__expf(v.w);
  }
  float Dd = Dv[d];
  float h[DS];
  size_t so = ((size_t)(b * NC + c) * DI + d) * DS;
#pragma unroll
  for (int n = 0; n < DS; n += 4) {
    float4 v = *(const float4*)(hin + so + n);
    h[n] = v.x; h[n+1] = v.y; h[n+2] = v.z; h[n+3] = v.w;
  }
  size_t row = (size_t)b * LSEQ + (size_t)c * CLEN;
  for (int t = 0; t < CLEN; ++t, ++row) {
    float dlt = delta[row * DI + d];
    float xv  = xsc[row * DI + d];
    float dx = dlt * xv;
    float y = 0.f;
#pragma unroll
    for (int n = 0; n < DS; ++n) {
      float Bn = bc[row * 32 + n];
      float Cn = bc[row * 32 + 16 + n];
      float dA = __expf(dlt * Av[n]);
      h[n] = dA * h[n] + dx * Bn;
      y += h[n] * Cn;
    }
    size_t ho = (row * DI + d) * DS;
#pragma unroll
    for (int n = 0; n < DS; n += 4)
      *(float4*)(hidden + ho + n) = make_float4(h[n], h[n+1], h[n+2], h[n+3]);
    float zv = xz[row * (2 * DI) + DI + d];
    float sz = zv / (1.f + __expf(-zv));
    float yv = (y + xv * Dd) * sz;
    ushort_t hb = bf16_rn(yv);
    yh[row * DI + d] = hb;
    yl[row * DI + d] = bf16_rn(yv - bf16_f32(hb));
  }
}

extern "C" void kernel_launch(void* const* d_in, const int* in_sizes, int n_in,
                              void* d_out, int out_size, void* d_ws, size_t ws_size,
                              hipStream_t stream) {
  const float* x         = (const float*)d_in[0];
  const float* in_proj_w = (const float*)d_in[1];
  const float* conv_w    = (const float*)d_in[2];
  const float* conv_b    = (const float*)d_in[3];
  const float* x_proj_w  = (const float*)d_in[4];
  const float* dt_proj_w = (const float*)d_in[5];
  const float* dt_proj_b = (const float*)d_in[6];
  const float* out_proj_w= (const float*)d_in[7];
  const float* A_log     = (const float*)d_in[8];
  const float* Dvec      = (const float*)d_in[9];

  float* out    = (float*)d_out;                            // (B,L,DM)
  float* hidden = (float*)d_out + (size_t)BSZ * LSEQ * DM;  // (B,L,DI,DS)

  float* ws  = (float*)d_ws;
  float* xz    = ws;                                   // (M, 2*DI)  8M floats
  float* xsc   = xz  + (size_t)MROWS * 2 * DI;         // (M, DI)    4M
  float* delta = xsc + (size_t)MROWS * DI;             // (M, DI)    4M
  float* bcbuf = delta + (size_t)MROWS * DI;           // (M, 32)
  float* hloc  = bcbuf + (size_t)MROWS * 32;           // (B,NC,DI,DS) 4M
  float* hin   = hloc + (size_t)BSZ * NC * DI * DS;    // (B,NC,DI,DS) 4M
  float* dsum  = hin  + (size_t)BSZ * NC * DI * DS;    // (B,NC,DI)  256K

  ushort_t* us = (ushort_t*)(dsum + (size_t)BSZ * NC * DI);
  ushort_t* xh   = us;                                 // 2M
  ushort_t* xl   = xh + (size_t)MROWS * DM;
  ushort_t* wih  = xl + (size_t)MROWS * DM;            // 4M
  ushort_t* wil  = wih + (size_t)2 * DI * DM;
  ushort_t* dth  = wil + (size_t)2 * DI * DM;          // 4M
  ushort_t* dtl  = dth + (size_t)DI * DI;
  ushort_t* oh   = dtl + (size_t)DI * DI;              // 2M
  ushort_t* ol   = oh + (size_t)DM * DI;
  ushort_t* xsch = ol + (size_t)DM * DI;               // 4M
  ushort_t* xscl = xsch + (size_t)MROWS * DI;
  ushort_t* yh   = xscl + (size_t)MROWS * DI;          // 4M
  ushort_t* yl   = yh + (size_t)MROWS * DI;

  dim3 blk(256);

  // pre-split inputs and weights to bf16 hi/lo
  split_f32<<<dim3((MROWS * DM) / 2048), blk, 0, stream>>>(x, xh, xl);
  split_f32<<<dim3((2 * DI * DM) / 2048), blk, 0, stream>>>(in_proj_w, wih, wil);
  split_f32<<<dim3((DI * DI) / 2048), blk, 0, stream>>>(dt_proj_w, dth, dtl);
  split_f32<<<dim3((DM * DI) / 2048), blk, 0, stream>>>(out_proj_w, oh, ol);

  // 1) xz = x @ in_proj_w^T   (M=2048, N=4096, K=1024)
  gemm_mfma<128, 128, 0><<<dim3((2 * DI) / 128, MROWS / 128), blk, 0, stream>>>(
      xh, xl, wih, wil, nullptr, xz, MROWS, 2 * DI, DM);

  // 2) depthwise conv + silu -> xsc (+ bf16 split)
  conv_silu<<<dim3((BSZ * LSEQ * DI) / 256), blk, 0, stream>>>(
      xz, conv_w, conv_b, xsc, xsch, xscl);

  // 3) delta = softplus(xsc @ dt_proj_w^T + b)   (M=2048, N=2048, K=2048)
  gemm_mfma<128, 128, 1><<<dim3(DI / 128, MROWS / 128), blk, 0, stream>>>(
      xsch, xscl, dth, dtl, dt_proj_b, delta, MROWS, DI, DI);

  // 4) BC = xsc @ x_proj_w^T   (N=32)
  gemm_bc<<<dim3(MROWS / 8), blk, 0, stream>>>(xsc, x_proj_w, bcbuf);

  // 5) chunked parallel scan -> hidden, y (bf16 split)
  scan_phaseA<<<dim3(DI / 256, NC, BSZ), blk, 0, stream>>>(
      delta, xsc, bcbuf, A_log, hloc, dsum);
  scan_phaseB<<<dim3((BSZ * DI * DS) / 256), blk, 0, stream>>>(
      hloc, dsum, A_log, hin);
  scan_phaseC<<<dim3(DI / 256, NC, BSZ), blk, 0, stream>>>(
      delta, xsc, bcbuf, xz, A_log, Dvec, hin, hidden, yh, yl);

  // 6) out = y @ out_proj_w^T   (M=2048, N=1024, K=2048), TM=64 for 256 blocks
  gemm_mfma<64, 128, 0><<<dim3(DM / 128, MROWS / 64), blk, 0, stream>>>(
      yh, yl, oh, ol, nullptr, out, MROWS, DM, DI);
}

// Round 5
// 416.374 us; speedup vs baseline: 4.3280x; 1.1938x over previous
//
#include <hip/hip_runtime.h>
#include <math.h>

#define BSZ 2
#define LSEQ 1024
#define DM 1024
#define DI 2048
#define DS 16
#define MROWS (BSZ * LSEQ)   // 2048
#define NC 64                // time chunks for parallel scan
#define CLEN (LSEQ / NC)     // 16
#define BK 32                // GEMM K-step

typedef __attribute__((ext_vector_type(8))) _Float16 half8;
typedef __attribute__((ext_vector_type(4))) float f32x4;

// async global->LDS, 16 bytes per lane; lds base must be wave-uniform
__device__ inline void gload16(const void* g, void* l) {
  __builtin_amdgcn_global_load_lds(
      (const __attribute__((address_space(1))) unsigned*)g,
      (__attribute__((address_space(3))) unsigned*)l, 16, 0, 0);
}

// ---------- fp32 -> fp16 (single) ----------
__global__ void cvt_f16(const float* __restrict__ in, _Float16* __restrict__ o) {
  int i = (blockIdx.x * 256 + threadIdx.x) * 8;
  f32x4 a = *(const f32x4*)(in + i);
  f32x4 b = *(const f32x4*)(in + i + 4);
  half8 h;
#pragma unroll
  for (int j = 0; j < 4; ++j) h[j] = (_Float16)a[j];
#pragma unroll
  for (int j = 0; j < 4; ++j) h[4 + j] = (_Float16)b[j];
  *(half8*)(o + i) = h;
}

// ---------- fp32 -> (fp16 hi, fp16 lo) split ----------
__global__ void split_f16(const float* __restrict__ in, _Float16* __restrict__ hi,
                          _Float16* __restrict__ lo) {
  int i = (blockIdx.x * 256 + threadIdx.x) * 8;
  f32x4 a = *(const f32x4*)(in + i);
  f32x4 b = *(const f32x4*)(in + i + 4);
  half8 h, l;
#pragma unroll
  for (int j = 0; j < 4; ++j) {
    _Float16 hb = (_Float16)a[j];
    h[j] = hb; l[j] = (_Float16)(a[j] - (float)hb);
  }
#pragma unroll
  for (int j = 0; j < 4; ++j) {
    _Float16 hb = (_Float16)b[j];
    h[4 + j] = hb; l[4 + j] = (_Float16)(b[j] - (float)hb);
  }
  *(half8*)(hi + i) = h;
  *(half8*)(lo + i) = l;
}

// ---------- fp16 2-term MFMA GEMM: C[M,N] = A[M,K] * W[N,K]^T ----------
// A single fp16; W pre-split hi/lo. C = Ah*Wh + Ah*Wl (= Ah*W).
// EPI: 0 = none, 1 = +bias softplus
template <int TM, int TN, int EPI>
__global__ __launch_bounds__(256) void gemm_mfma(
    const _Float16* __restrict__ Ag, const _Float16* __restrict__ Whg,
    const _Float16* __restrict__ Wlg, const float* __restrict__ bias,
    float* __restrict__ C, int M, int N, int K) {
  constexpr int FI = TM / 32, FJ = TN / 32;
  __shared__ _Float16 Ah[TM * BK], Wh[TN * BK], Wl[TN * BK];
  int tid = threadIdx.x, lane = tid & 63, wid = tid >> 6;
  int m0 = blockIdx.y * TM, n0 = blockIdx.x * TN;
  int wm = (wid >> 1) * (TM / 2), wn = (wid & 1) * (TN / 2);
  int fr = lane & 15, fq = lane >> 4;

  f32x4 acc[FI][FJ];
#pragma unroll
  for (int i = 0; i < FI; ++i)
#pragma unroll
    for (int j = 0; j < FJ; ++j) acc[i][j] = (f32x4){0.f, 0.f, 0.f, 0.f};

  for (int k0 = 0; k0 < K; k0 += BK) {
#pragma unroll
    for (int q = 0; q < TM / 64; ++q) {
      int i = q * 256 + wid * 64 + lane;
      int row = i >> 2, col = (i & 3) * 8;
      size_t go = (size_t)(m0 + row) * K + k0 + col;
      int lo8 = (q * 256 + wid * 64) * 8;       // wave-uniform LDS elem offset
      gload16(Ag + go, &Ah[lo8]);
    }
#pragma unroll
    for (int q = 0; q < TN / 64; ++q) {
      int i = q * 256 + wid * 64 + lane;
      int row = i >> 2, col = (i & 3) * 8;
      size_t go = (size_t)(n0 + row) * K + k0 + col;
      int lo8 = (q * 256 + wid * 64) * 8;
      gload16(Whg + go, &Wh[lo8]);
      gload16(Wlg + go, &Wl[lo8]);
    }
    __syncthreads();

    half8 ah[FI], wh[FJ], wl[FJ];
#pragma unroll
    for (int f = 0; f < FI; ++f) {
      int ra = (wm + f * 16 + fr) * BK + fq * 8;
      ah[f] = *(const half8*)&Ah[ra];
    }
#pragma unroll
    for (int f = 0; f < FJ; ++f) {
      int rw = (wn + f * 16 + fr) * BK + fq * 8;
      wh[f] = *(const half8*)&Wh[rw];
      wl[f] = *(const half8*)&Wl[rw];
    }
#pragma unroll
    for (int i = 0; i < FI; ++i)
#pragma unroll
      for (int j = 0; j < FJ; ++j) {
        acc[i][j] = __builtin_amdgcn_mfma_f32_16x16x32_f16(ah[i], wh[j], acc[i][j], 0, 0, 0);
        acc[i][j] = __builtin_amdgcn_mfma_f32_16x16x32_f16(ah[i], wl[j], acc[i][j], 0, 0, 0);
      }
    __syncthreads();
  }

#pragma unroll
  for (int i = 0; i < FI; ++i) {
    int m = m0 + wm + i * 16 + fq * 4;
#pragma unroll
    for (int j = 0; j < FJ; ++j) {
      int n = n0 + wn + j * 16 + fr;
#pragma unroll
      for (int r = 0; r < 4; ++r) {
        float v = acc[i][j][r];
        if (EPI == 1) {
          v += bias[n];
          v = (v > 20.f) ? v : log1pf(expf(v));   // softplus
        }
        C[(size_t)(m + r) * N + n] = v;
      }
    }
  }
}

// ---------- depthwise conv1d k=3 pad=1 + bias + silu; fused fp16 cvt ----------
__global__ void conv_silu(const float* __restrict__ xz, const float* __restrict__ cw,
                          const float* __restrict__ cb, float* __restrict__ xsc,
                          _Float16* __restrict__ xsch) {
  int idx = blockIdx.x * 256 + threadIdx.x;  // over B*L*DI
  int d = idx & (DI - 1);
  int bt = idx >> 11;           // row index (b*L + t)
  int t = bt & (LSEQ - 1);
  const float* base = xz + (size_t)bt * (2 * DI) + d;  // xs part: cols [0,DI)
  float acc = cb[d];
  float w0 = cw[d * 3 + 0], w1 = cw[d * 3 + 1], w2 = cw[d * 3 + 2];
  if (t > 0) acc += base[-(2 * DI)] * w0;
  acc += base[0] * w1;
  if (t < LSEQ - 1) acc += base[2 * DI] * w2;
  float s = acc / (1.f + __expf(-acc));   // silu
  xsc[idx] = s;
  xsch[idx] = (_Float16)s;
}

// ---------- small GEMM: BC[M,32] = xsc[M,DI] * x_proj_w[32,DI]^T ----------
__global__ void gemm_bc(const float* __restrict__ A, const float* __restrict__ W,
                        float* __restrict__ C) {
  int tid = threadIdx.x;          // 256 threads: 32 n x 8 rows
  int n = tid & 31;
  int r = tid >> 5;
  int m = blockIdx.x * 8 + r;
  const f32x4* a = (const f32x4*)(A + (size_t)m * DI);
  const f32x4* w = (const f32x4*)(W + (size_t)n * DI);
  float acc = 0.f;
#pragma unroll 4
  for (int k = 0; k < DI / 4; ++k) {
    f32x4 av = a[k], wv = w[k];
    acc += av[0] * wv[0] + av[1] * wv[1] + av[2] * wv[2] + av[3] * wv[3];
  }
  C[m * 32 + n] = acc;
}

// ---------- chunked parallel scan ----------
__global__ void scan_phaseA(const float* __restrict__ delta,
                            const float* __restrict__ xsc,
                            const float* __restrict__ bc,
                            const float* __restrict__ A_log,
                            float* __restrict__ hloc,
                            float* __restrict__ dsum) {
  int tid = threadIdx.x;
  int d = blockIdx.x * 256 + tid;
  int c = blockIdx.y;
  int b = blockIdx.z;
  float Av[DS];
#pragma unroll
  for (int n = 0; n < DS; n += 4) {
    float4 v = *(const float4*)(A_log + d * DS + n);
    Av[n] = -__expf(v.x); Av[n+1] = -__expf(v.y);
    Av[n+2] = -__expf(v.z); Av[n+3] = -__expf(v.w);
  }
  float h[DS] = {};
  float sd = 0.f;
  size_t row = (size_t)b * LSEQ + (size_t)c * CLEN;
  for (int t = 0; t < CLEN; ++t, ++row) {
    float dlt = delta[row * DI + d];
    float xv  = xsc[row * DI + d];
    float dx = dlt * xv;
    sd += dlt;
#pragma unroll
    for (int n = 0; n < DS; ++n) {
      float Bn = bc[row * 32 + n];
      float dA = __expf(dlt * Av[n]);
      h[n] = dA * h[n] + dx * Bn;
    }
  }
  size_t o = ((size_t)(b * NC + c) * DI + d) * DS;
#pragma unroll
  for (int n = 0; n < DS; n += 4)
    *(float4*)(hloc + o + n) = make_float4(h[n], h[n+1], h[n+2], h[n+3]);
  dsum[(b * NC + c) * DI + d] = sd;
}

__global__ void scan_phaseB(const float* __restrict__ hloc,
                            const float* __restrict__ dsum,
                            const float* __restrict__ A_log,
                            float* __restrict__ hin) {
  int gid = blockIdx.x * 256 + threadIdx.x;   // over B*DI*DS
  int n = gid & 15;
  int d = (gid >> 4) & (DI - 1);
  int b = gid >> 15;
  float Av = -__expf(A_log[d * DS + n]);
  float h = 0.f;
  for (int c = 0; c < NC; ++c) {
    size_t o = ((size_t)(b * NC + c) * DI + d) * DS + n;
    hin[o] = h;
    float p = __expf(Av * dsum[(b * NC + c) * DI + d]);
    h = hloc[o] + p * h;
  }
}

// Phase C: scan within chunk seeded with hin; hidden written coalesced via LDS;
// fused y = (sum h*C + x*D) * silu(z) emitted as fp16 for the out_proj GEMM.
#define HS_STRIDE 20   // floats; 80B: 16B-aligned, breaks 64B bank pattern
__global__ void scan_phaseC(const float* __restrict__ delta,
                            const float* __restrict__ xsc,
                            const float* __restrict__ bc,
                            const float* __restrict__ xz,
                            const float* __restrict__ A_log,
                            const float* __restrict__ Dv,
                            const float* __restrict__ hin,
                            float* __restrict__ hidden,
                            _Float16* __restrict__ yh) {
  __shared__ float hs[256 * HS_STRIDE];
  int tid = threadIdx.x;
  int d0 = blockIdx.x * 256;
  int d = d0 + tid;
  int c = blockIdx.y;
  int b = blockIdx.z;
  float Av[DS];
#pragma unroll
  for (int n = 0; n < DS; n += 4) {
    float4 v = *(const float4*)(A_log + d * DS + n);
    Av[n] = -__expf(v.x); Av[n+1] = -__expf(v.y);
    Av[n+2] = -__expf(v.z); Av[n+3] = -__expf(v.w);
  }
  float Dd = Dv[d];
  float h[DS];
  size_t so = ((size_t)(b * NC + c) * DI + d) * DS;
#pragma unroll
  for (int n = 0; n < DS; n += 4) {
    float4 v = *(const float4*)(hin + so + n);
    h[n] = v.x; h[n+1] = v.y; h[n+2] = v.z; h[n+3] = v.w;
  }
  size_t row = (size_t)b * LSEQ + (size_t)c * CLEN;
  for (int t = 0; t < CLEN; ++t, ++row) {
    float dlt = delta[row * DI + d];
    float xv  = xsc[row * DI + d];
    float dx = dlt * xv;
    float y = 0.f;
#pragma unroll
    for (int n = 0; n < DS; ++n) {
      float Bn = bc[row * 32 + n];
      float Cn = bc[row * 32 + 16 + n];
      float dA = __expf(dlt * Av[n]);
      h[n] = dA * h[n] + dx * Bn;
      y += h[n] * Cn;
    }
    // stage h into LDS, then cooperatively write 16KB contiguous
#pragma unroll
    for (int n = 0; n < DS; n += 4)
      *(float4*)&hs[tid * HS_STRIDE + n] = make_float4(h[n], h[n+1], h[n+2], h[n+3]);
    __syncthreads();
    size_t basef = ((size_t)row * DI + d0) * DS;   // 4096 floats for this block
#pragma unroll
    for (int k = 0; k < 4; ++k) {
      int f4 = tid + 256 * k;            // float4 index within slab
      int owner = f4 >> 2;
      int elem = (f4 & 3) * 4;
      float4 v = *(const float4*)&hs[owner * HS_STRIDE + elem];
      *(float4*)&hidden[basef + (size_t)f4 * 4] = v;
    }
    __syncthreads();
    float zv = xz[row * (2 * DI) + DI + d];
    float sz = zv / (1.f + __expf(-zv));
    yh[row * DI + d] = (_Float16)((y + xv * Dd) * sz);
  }
}

extern "C" void kernel_launch(void* const* d_in, const int* in_sizes, int n_in,
                              void* d_out, int out_size, void* d_ws, size_t ws_size,
                              hipStream_t stream) {
  const float* x         = (const float*)d_in[0];
  const float* in_proj_w = (const float*)d_in[1];
  const float* conv_w    = (const float*)d_in[2];
  const float* conv_b    = (const float*)d_in[3];
  const float* x_proj_w  = (const float*)d_in[4];
  const float* dt_proj_w = (const float*)d_in[5];
  const float* dt_proj_b = (const float*)d_in[6];
  const float* out_proj_w= (const float*)d_in[7];
  const float* A_log     = (const float*)d_in[8];
  const float* Dvec      = (const float*)d_in[9];

  float* out    = (float*)d_out;                            // (B,L,DM)
  float* hidden = (float*)d_out + (size_t)BSZ * LSEQ * DM;  // (B,L,DI,DS)

  float* ws  = (float*)d_ws;
  float* xz    = ws;                                   // (M, 2*DI)  8M floats
  float* xsc   = xz  + (size_t)MROWS * 2 * DI;         // (M, DI)    4M
  float* delta = xsc + (size_t)MROWS * DI;             // (M, DI)    4M
  float* bcbuf = delta + (size_t)MROWS * DI;           // (M, 32)
  float* hloc  = bcbuf + (size_t)MROWS * 32;           // (B,NC,DI,DS) 4M
  float* hin   = hloc + (size_t)BSZ * NC * DI * DS;    // (B,NC,DI,DS) 4M
  float* dsum  = hin  + (size_t)BSZ * NC * DI * DS;    // (B,NC,DI)  256K

  _Float16* hp = (_Float16*)(dsum + (size_t)BSZ * NC * DI);
  _Float16* xh   = hp;                                 // (M,DM)    2M
  _Float16* wih  = xh + (size_t)MROWS * DM;            // (2DI,DM)  4M
  _Float16* wil  = wih + (size_t)2 * DI * DM;
  _Float16* dth  = wil + (size_t)2 * DI * DM;          // (DI,DI)   4M
  _Float16* dtl  = dth + (size_t)DI * DI;
  _Float16* oh   = dtl + (size_t)DI * DI;              // (DM,DI)   2M
  _Float16* ol   = oh + (size_t)DM * DI;
  _Float16* xsch = ol + (size_t)DM * DI;               // (M,DI)    4M
  _Float16* yh   = xsch + (size_t)MROWS * DI;          // (M,DI)    4M

  dim3 blk(256);

  // pre-convert activations / pre-split weights to fp16
  cvt_f16<<<dim3((MROWS * DM) / 2048), blk, 0, stream>>>(x, xh);
  split_f16<<<dim3((2 * DI * DM) / 2048), blk, 0, stream>>>(in_proj_w, wih, wil);
  split_f16<<<dim3((DI * DI) / 2048), blk, 0, stream>>>(dt_proj_w, dth, dtl);
  split_f16<<<dim3((DM * DI) / 2048), blk, 0, stream>>>(out_proj_w, oh, ol);

  // 1) xz = x @ in_proj_w^T   (M=2048, N=4096, K=1024)
  gemm_mfma<128, 128, 0><<<dim3((2 * DI) / 128, MROWS / 128), blk, 0, stream>>>(
      xh, wih, wil, nullptr, xz, MROWS, 2 * DI, DM);

  // 2) depthwise conv + silu -> xsc (+ fp16)
  conv_silu<<<dim3((BSZ * LSEQ * DI) / 256), blk, 0, stream>>>(
      xz, conv_w, conv_b, xsc, xsch);

  // 3) delta = softplus(xsc @ dt_proj_w^T + b)   (M=2048, N=2048, K=2048)
  gemm_mfma<128, 128, 1><<<dim3(DI / 128, MROWS / 128), blk, 0, stream>>>(
      xsch, dth, dtl, dt_proj_b, delta, MROWS, DI, DI);

  // 4) BC = xsc @ x_proj_w^T   (N=32)
  gemm_bc<<<dim3(MROWS / 8), blk, 0, stream>>>(xsc, x_proj_w, bcbuf);

  // 5) chunked parallel scan -> hidden, y (fp16)
  scan_phaseA<<<dim3(DI / 256, NC, BSZ), blk, 0, stream>>>(
      delta, xsc, bcbuf, A_log, hloc, dsum);
  scan_phaseB<<<dim3((BSZ * DI * DS) / 256), blk, 0, stream>>>(
      hloc, dsum, A_log, hin);
  scan_phaseC<<<dim3(DI / 256, NC, BSZ), blk, 0, stream>>>(
      delta, xsc, bcbuf, xz, A_log, Dvec, hin, hidden, yh);

  // 6) out = y @ out_proj_w^T   (M=2048, N=1024, K=2048), TM=64 for 256 blocks
  gemm_mfma<64, 128, 0><<<dim3(DM / 128, MROWS / 64), blk, 0, stream>>>(
      yh, oh, ol, nullptr, out, MROWS, DM, DI);
}

// Round 6
// 372.307 us; speedup vs baseline: 4.8403x; 1.1184x over previous
//
#include <hip/hip_runtime.h>
#include <math.h>

#define BSZ 2
#define LSEQ 1024
#define DM 1024
#define DI 2048
#define DS 16
#define MROWS (BSZ * LSEQ)   // 2048
#define NC 64                // time chunks for parallel scan
#define CLEN (LSEQ / NC)     // 16
#define BK 32                // GEMM K-step

typedef __attribute__((ext_vector_type(8))) _Float16 half8;
typedef __attribute__((ext_vector_type(4))) float f32x4;

// async global->LDS, 16 bytes per lane; lds base must be wave-uniform
__device__ inline void gload16(const void* g, void* l) {
  __builtin_amdgcn_global_load_lds(
      (const __attribute__((address_space(1))) unsigned*)g,
      (__attribute__((address_space(3))) unsigned*)l, 16, 0, 0);
}

// ---------- merged prep: fp32 -> fp16 cvt / hi+lo split ----------
__device__ inline void cvt8_at(const float* __restrict__ in, _Float16* __restrict__ o,
                               int i) {
  f32x4 a = *(const f32x4*)(in + i);
  f32x4 b = *(const f32x4*)(in + i + 4);
  half8 h;
#pragma unroll
  for (int j = 0; j < 4; ++j) h[j] = (_Float16)a[j];
#pragma unroll
  for (int j = 0; j < 4; ++j) h[4 + j] = (_Float16)b[j];
  *(half8*)(o + i) = h;
}
__device__ inline void split8_at(const float* __restrict__ in,
                                 _Float16* __restrict__ hi,
                                 _Float16* __restrict__ lo, int i) {
  f32x4 a = *(const f32x4*)(in + i);
  f32x4 b = *(const f32x4*)(in + i + 4);
  half8 h, l;
#pragma unroll
  for (int j = 0; j < 4; ++j) {
    _Float16 hb = (_Float16)a[j];
    h[j] = hb; l[j] = (_Float16)(a[j] - (float)hb);
  }
#pragma unroll
  for (int j = 0; j < 4; ++j) {
    _Float16 hb = (_Float16)b[j];
    h[4 + j] = hb; l[4 + j] = (_Float16)(b[j] - (float)hb);
  }
  *(half8*)(hi + i) = h;
  *(half8*)(lo + i) = l;
}

__global__ void prep(const float* __restrict__ x, const float* __restrict__ wi,
                     const float* __restrict__ wdt, const float* __restrict__ wo,
                     _Float16* __restrict__ xh,
                     _Float16* __restrict__ wih, _Float16* __restrict__ wil,
                     _Float16* __restrict__ dth, _Float16* __restrict__ dtl,
                     _Float16* __restrict__ oh, _Float16* __restrict__ ol) {
  int blk = blockIdx.x, tid = threadIdx.x;
  if (blk < 1024) {                       // x: 2M elems
    cvt8_at(x, xh, (blk * 256 + tid) * 8);
  } else if (blk < 3072) {                // in_proj_w: 4M
    split8_at(wi, wih, wil, ((blk - 1024) * 256 + tid) * 8);
  } else if (blk < 5120) {                // dt_proj_w: 4M
    split8_at(wdt, dth, dtl, ((blk - 3072) * 256 + tid) * 8);
  } else {                                // out_proj_w: 2M
    split8_at(wo, oh, ol, ((blk - 5120) * 256 + tid) * 8);
  }
}

// ---------- fp16 2-term MFMA GEMM: C[M,N] = A[M,K] * W[N,K]^T ----------
// A single fp16; W pre-split hi/lo. Split-K via blockIdx.z (partials stacked
// in C). Raw partial write; epilogue lives in reduce2.
template <int TM, int TN>
__global__ __launch_bounds__(256) void gemm_mfma(
    const _Float16* __restrict__ Ag, const _Float16* __restrict__ Whg,
    const _Float16* __restrict__ Wlg, float* __restrict__ C,
    int M, int N, int K) {
  constexpr int FI = TM / 32, FJ = TN / 32;
  __shared__ _Float16 Ah[TM * BK], Wh[TN * BK], Wl[TN * BK];
  int tid = threadIdx.x, lane = tid & 63, wid = tid >> 6;

  // split-K slice
  int ksl = K / gridDim.z;
  int kBeg = blockIdx.z * ksl, kEnd = kBeg + ksl;
  C += (size_t)blockIdx.z * M * N;

  // XCD-aware swizzle (nwg is a multiple of 8 for all our launches)
  int gx = gridDim.x, nwg = gx * gridDim.y;
  int id = blockIdx.y * gx + blockIdx.x;
  int swz = (id & 7) * (nwg >> 3) + (id >> 3);
  int m0 = (swz / gx) * TM, n0 = (swz % gx) * TN;

  int wm = (wid >> 1) * (TM / 2), wn = (wid & 1) * (TN / 2);
  int fr = lane & 15, fq = lane >> 4;

  f32x4 acc[FI][FJ];
#pragma unroll
  for (int i = 0; i < FI; ++i)
#pragma unroll
    for (int j = 0; j < FJ; ++j) acc[i][j] = (f32x4){0.f, 0.f, 0.f, 0.f};

  for (int k0 = kBeg; k0 < kEnd; k0 += BK) {
#pragma unroll
    for (int q = 0; q < TM / 64; ++q) {
      int i = q * 256 + wid * 64 + lane;
      int row = i >> 2, col = (i & 3) * 8;
      size_t go = (size_t)(m0 + row) * K + k0 + col;
      int lo8 = (q * 256 + wid * 64) * 8;       // wave-uniform LDS elem offset
      gload16(Ag + go, &Ah[lo8]);
    }
#pragma unroll
    for (int q = 0; q < TN / 64; ++q) {
      int i = q * 256 + wid * 64 + lane;
      int row = i >> 2, col = (i & 3) * 8;
      size_t go = (size_t)(n0 + row) * K + k0 + col;
      int lo8 = (q * 256 + wid * 64) * 8;
      gload16(Whg + go, &Wh[lo8]);
      gload16(Wlg + go, &Wl[lo8]);
    }
    __syncthreads();

    half8 ah[FI], wh[FJ], wl[FJ];
#pragma unroll
    for (int f = 0; f < FI; ++f) {
      int ra = (wm + f * 16 + fr) * BK + fq * 8;
      ah[f] = *(const half8*)&Ah[ra];
    }
#pragma unroll
    for (int f = 0; f < FJ; ++f) {
      int rw = (wn + f * 16 + fr) * BK + fq * 8;
      wh[f] = *(const half8*)&Wh[rw];
      wl[f] = *(const half8*)&Wl[rw];
    }
#pragma unroll
    for (int i = 0; i < FI; ++i)
#pragma unroll
      for (int j = 0; j < FJ; ++j) {
        acc[i][j] = __builtin_amdgcn_mfma_f32_16x16x32_f16(ah[i], wh[j], acc[i][j], 0, 0, 0);
        acc[i][j] = __builtin_amdgcn_mfma_f32_16x16x32_f16(ah[i], wl[j], acc[i][j], 0, 0, 0);
      }
    __syncthreads();
  }

#pragma unroll
  for (int i = 0; i < FI; ++i) {
    int m = m0 + wm + i * 16 + fq * 4;
#pragma unroll
    for (int j = 0; j < FJ; ++j) {
      int n = n0 + wn + j * 16 + fr;
#pragma unroll
      for (int r = 0; r < 4; ++r)
        C[(size_t)(m + r) * N + n] = acc[i][j][r];
    }
  }
}

// ---------- split-K reduction: C = P0+P1 (+bias, softplus) ----------
template <int SOFTPLUS>
__global__ void reduce2(const float* __restrict__ P, const float* __restrict__ bias,
                        float* __restrict__ C, int MN, int N) {
  int i = (blockIdx.x * 256 + threadIdx.x) * 4;
  f32x4 a = *(const f32x4*)(P + i);
  f32x4 b = *(const f32x4*)(P + MN + i);
  f32x4 v = a + b;
  if (SOFTPLUS) {
    f32x4 bs = *(const f32x4*)(bias + (i & (N - 1)));
#pragma unroll
    for (int j = 0; j < 4; ++j) {
      float t = v[j] + bs[j];
      v[j] = (t > 20.f) ? t : log1pf(expf(t));
    }
  }
  *(f32x4*)(C + i) = v;
}

// ---------- depthwise conv1d k=3 pad=1 + bias + silu; fused fp16 cvt ----------
__global__ void conv_silu(const float* __restrict__ xz, const float* __restrict__ cw,
                          const float* __restrict__ cb, float* __restrict__ xsc,
                          _Float16* __restrict__ xsch) {
  int idx = blockIdx.x * 256 + threadIdx.x;  // over B*L*DI
  int d = idx & (DI - 1);
  int bt = idx >> 11;           // row index (b*L + t)
  int t = bt & (LSEQ - 1);
  const float* base = xz + (size_t)bt * (2 * DI) + d;  // xs part: cols [0,DI)
  float acc = cb[d];
  float w0 = cw[d * 3 + 0], w1 = cw[d * 3 + 1], w2 = cw[d * 3 + 2];
  if (t > 0) acc += base[-(2 * DI)] * w0;
  acc += base[0] * w1;
  if (t < LSEQ - 1) acc += base[2 * DI] * w2;
  float s = acc / (1.f + __expf(-acc));   // silu
  xsc[idx] = s;
  xsch[idx] = (_Float16)s;
}

// ---------- small GEMM: BC[M,32] = xsc[M,DI](fp16) * x_proj_w[32,DI]^T ----------
__global__ void gemm_bc(const _Float16* __restrict__ A, const float* __restrict__ W,
                        float* __restrict__ C) {
  int tid = threadIdx.x;          // 256 threads: 32 n x 8 rows
  int n = tid & 31;
  int r = tid >> 5;
  int m = blockIdx.x * 8 + r;
  const half8* a = (const half8*)(A + (size_t)m * DI);
  const f32x4* w = (const f32x4*)(W + (size_t)n * DI);
  float acc = 0.f;
#pragma unroll 2
  for (int k = 0; k < DI / 8; ++k) {
    half8 av = a[k];
    f32x4 w0 = w[2 * k], w1 = w[2 * k + 1];
    acc += (float)av[0] * w0[0] + (float)av[1] * w0[1] +
           (float)av[2] * w0[2] + (float)av[3] * w0[3] +
           (float)av[4] * w1[0] + (float)av[5] * w1[1] +
           (float)av[6] * w1[2] + (float)av[7] * w1[3];
  }
  C[m * 32 + n] = acc;
}

// ---------- chunked parallel scan ----------
__global__ void scan_phaseA(const float* __restrict__ delta,
                            const float* __restrict__ xsc,
                            const float* __restrict__ bc,
                            const float* __restrict__ A_log,
                            float* __restrict__ hloc,
                            float* __restrict__ dsum) {
  int tid = threadIdx.x;
  int d = blockIdx.x * 256 + tid;
  int c = blockIdx.y;
  int b = blockIdx.z;
  float Av[DS];
#pragma unroll
  for (int n = 0; n < DS; n += 4) {
    float4 v = *(const float4*)(A_log + d * DS + n);
    Av[n] = -__expf(v.x); Av[n+1] = -__expf(v.y);
    Av[n+2] = -__expf(v.z); Av[n+3] = -__expf(v.w);
  }
  float h[DS] = {};
  float sd = 0.f;
  size_t row = (size_t)b * LSEQ + (size_t)c * CLEN;
  for (int t = 0; t < CLEN; ++t, ++row) {
    float dlt = delta[row * DI + d];
    float xv  = xsc[row * DI + d];
    float dx = dlt * xv;
    sd += dlt;
#pragma unroll
    for (int n = 0; n < DS; ++n) {
      float Bn = bc[row * 32 + n];
      float dA = __expf(dlt * Av[n]);
      h[n] = dA * h[n] + dx * Bn;
    }
  }
  size_t o = ((size_t)(b * NC + c) * DI + d) * DS;
#pragma unroll
  for (int n = 0; n < DS; n += 4)
    *(float4*)(hloc + o + n) = make_float4(h[n], h[n+1], h[n+2], h[n+3]);
  dsum[(b * NC + c) * DI + d] = sd;
}

__global__ void scan_phaseB(const float* __restrict__ hloc,
                            const float* __restrict__ dsum,
                            const float* __restrict__ A_log,
                            float* __restrict__ hin) {
  int gid = blockIdx.x * 256 + threadIdx.x;   // over B*DI*DS
  int n = gid & 15;
  int d = (gid >> 4) & (DI - 1);
  int b = gid >> 15;
  float Av = -__expf(A_log[d * DS + n]);
  float h = 0.f;
  for (int c = 0; c < NC; ++c) {
    size_t o = ((size_t)(b * NC + c) * DI + d) * DS + n;
    hin[o] = h;
    float p = __expf(Av * dsum[(b * NC + c) * DI + d]);
    h = hloc[o] + p * h;
  }
}

// Phase C: scan within chunk seeded with hin; hidden written coalesced via LDS;
// fused y = (sum h*C + x*D) * silu(z) emitted as fp16 for the out_proj GEMM.
#define HS_STRIDE 20   // floats; 80B: 16B-aligned, breaks 64B bank pattern
__global__ void scan_phaseC(const float* __restrict__ delta,
                            const float* __restrict__ xsc,
                            const float* __restrict__ bc,
                            const float* __restrict__ xz,
                            const float* __restrict__ A_log,
                            const float* __restrict__ Dv,
                            const float* __restrict__ hin,
                            float* __restrict__ hidden,
                            _Float16* __restrict__ yh) {
  __shared__ float hs[256 * HS_STRIDE];
  int tid = threadIdx.x;
  int d0 = blockIdx.x * 256;
  int d = d0 + tid;
  int c = blockIdx.y;
  int b = blockIdx.z;
  float Av[DS];
#pragma unroll
  for (int n = 0; n < DS; n += 4) {
    float4 v = *(const float4*)(A_log + d * DS + n);
    Av[n] = -__expf(v.x); Av[n+1] = -__expf(v.y);
    Av[n+2] = -__expf(v.z); Av[n+3] = -__expf(v.w);
  }
  float Dd = Dv[d];
  float h[DS];
  size_t so = ((size_t)(b * NC + c) * DI + d) * DS;
#pragma unroll
  for (int n = 0; n < DS; n += 4) {
    float4 v = *(const float4*)(hin + so + n);
    h[n] = v.x; h[n+1] = v.y; h[n+2] = v.z; h[n+3] = v.w;
  }
  size_t row = (size_t)b * LSEQ + (size_t)c * CLEN;
  for (int t = 0; t < CLEN; ++t, ++row) {
    float dlt = delta[row * DI + d];
    float xv  = xsc[row * DI + d];
    float dx = dlt * xv;
    float y = 0.f;
#pragma unroll
    for (int n = 0; n < DS; ++n) {
      float Bn = bc[row * 32 + n];
      float Cn = bc[row * 32 + 16 + n];
      float dA = __expf(dlt * Av[n]);
      h[n] = dA * h[n] + dx * Bn;
      y += h[n] * Cn;
    }
    // stage h into LDS, then cooperatively write 16KB contiguous
#pragma unroll
    for (int n = 0; n < DS; n += 4)
      *(float4*)&hs[tid * HS_STRIDE + n] = make_float4(h[n], h[n+1], h[n+2], h[n+3]);
    __syncthreads();
    size_t basef = ((size_t)row * DI + d0) * DS;   // 4096 floats for this block
#pragma unroll
    for (int k = 0; k < 4; ++k) {
      int f4 = tid + 256 * k;            // float4 index within slab
      int owner = f4 >> 2;
      int elem = (f4 & 3) * 4;
      float4 v = *(const float4*)&hs[owner * HS_STRIDE + elem];
      *(float4*)&hidden[basef + (size_t)f4 * 4] = v;
    }
    __syncthreads();
    float zv = xz[row * (2 * DI) + DI + d];
    float sz = zv / (1.f + __expf(-zv));
    yh[row * DI + d] = (_Float16)((y + xv * Dd) * sz);
  }
}

extern "C" void kernel_launch(void* const* d_in, const int* in_sizes, int n_in,
                              void* d_out, int out_size, void* d_ws, size_t ws_size,
                              hipStream_t stream) {
  const float* x         = (const float*)d_in[0];
  const float* in_proj_w = (const float*)d_in[1];
  const float* conv_w    = (const float*)d_in[2];
  const float* conv_b    = (const float*)d_in[3];
  const float* x_proj_w  = (const float*)d_in[4];
  const float* dt_proj_w = (const float*)d_in[5];
  const float* dt_proj_b = (const float*)d_in[6];
  const float* out_proj_w= (const float*)d_in[7];
  const float* A_log     = (const float*)d_in[8];
  const float* Dvec      = (const float*)d_in[9];

  float* out    = (float*)d_out;                            // (B,L,DM)
  float* hidden = (float*)d_out + (size_t)BSZ * LSEQ * DM;  // (B,L,DI,DS)

  float* ws  = (float*)d_ws;
  float* xz    = ws;                                   // (M, 2*DI)  8M floats
  float* xsc   = xz  + (size_t)MROWS * 2 * DI;         // (M, DI)    4M
  float* delta = xsc + (size_t)MROWS * DI;             // (M, DI)    4M
  float* bcbuf = delta + (size_t)MROWS * DI;           // (M, 32)
  float* hloc  = bcbuf + (size_t)MROWS * 32;           // (B,NC,DI,DS) 4M
  float* hin   = hloc + (size_t)BSZ * NC * DI * DS;    // (B,NC,DI,DS) 4M
  float* dsum  = hin  + (size_t)BSZ * NC * DI * DS;    // (B,NC,DI)  256K
  float* dtP   = dsum + (size_t)BSZ * NC * DI;         // 2x(M,DI)   8M
  float* outP  = dtP + (size_t)2 * MROWS * DI;         // 2x(M,DM)   4M

  _Float16* hp = (_Float16*)(outP + (size_t)2 * MROWS * DM);
  _Float16* xh   = hp;                                 // (M,DM)    2M
  _Float16* wih  = xh + (size_t)MROWS * DM;            // (2DI,DM)  4M
  _Float16* wil  = wih + (size_t)2 * DI * DM;
  _Float16* dth  = wil + (size_t)2 * DI * DM;          // (DI,DI)   4M
  _Float16* dtl  = dth + (size_t)DI * DI;
  _Float16* oh   = dtl + (size_t)DI * DI;              // (DM,DI)   2M
  _Float16* ol   = oh + (size_t)DM * DI;
  _Float16* xsch = ol + (size_t)DM * DI;               // (M,DI)    4M
  _Float16* yh   = xsch + (size_t)MROWS * DI;          // (M,DI)    4M

  dim3 blk(256);

  // 0) merged prep: cvt x, split the three weight matrices
  prep<<<dim3(6144), blk, 0, stream>>>(x, in_proj_w, dt_proj_w, out_proj_w,
                                       xh, wih, wil, dth, dtl, oh, ol);

  // 1) xz = x @ in_proj_w^T   (M=2048, N=4096, K=1024); 512 blocks
  gemm_mfma<128, 128><<<dim3((2 * DI) / 128, MROWS / 128, 1), blk, 0, stream>>>(
      xh, wih, wil, xz, MROWS, 2 * DI, DM);

  // 2) depthwise conv + silu -> xsc (+ fp16)
  conv_silu<<<dim3((BSZ * LSEQ * DI) / 256), blk, 0, stream>>>(
      xz, conv_w, conv_b, xsc, xsch);

  // 3) dt partials (split-K=2; 512 blocks), then delta = softplus(P0+P1+b)
  gemm_mfma<128, 128><<<dim3(DI / 128, MROWS / 128, 2), blk, 0, stream>>>(
      xsch, dth, dtl, dtP, MROWS, DI, DI);
  reduce2<1><<<dim3((MROWS * DI) / 1024), blk, 0, stream>>>(
      dtP, dt_proj_b, delta, MROWS * DI, DI);

  // 4) BC = xsc @ x_proj_w^T   (N=32)
  gemm_bc<<<dim3(MROWS / 8), blk, 0, stream>>>(xsch, x_proj_w, bcbuf);

  // 5) chunked parallel scan -> hidden, y (fp16)
  scan_phaseA<<<dim3(DI / 256, NC, BSZ), blk, 0, stream>>>(
      delta, xsc, bcbuf, A_log, hloc, dsum);
  scan_phaseB<<<dim3((BSZ * DI * DS) / 256), blk, 0, stream>>>(
      hloc, dsum, A_log, hin);
  scan_phaseC<<<dim3(DI / 256, NC, BSZ), blk, 0, stream>>>(
      delta, xsc, bcbuf, xz, A_log, Dvec, hin, hidden, yh);

  // 6) out partials (split-K=2, TM=64; 512 blocks), then out = P0+P1
  gemm_mfma<64, 128><<<dim3(DM / 128, MROWS / 64, 2), blk, 0, stream>>>(
      yh, oh, ol, outP, MROWS, DM, DI);
  reduce2<0><<<dim3((MROWS * DM) / 1024), blk, 0, stream>>>(
      outP, nullptr, out, MROWS * DM, DM);
}

// Round 7
// 367.381 us; speedup vs baseline: 4.9052x; 1.0134x over previous
//
#include <hip/hip_runtime.h>
#include <math.h>

#define BSZ 2
#define LSEQ 1024
#define DM 1024
#define DI 2048
#define DS 16
#define MROWS (BSZ * LSEQ)   // 2048
#define NC 64                // time chunks for parallel scan
#define CLEN (LSEQ / NC)     // 16
#define BK 32                // GEMM K-step

typedef __attribute__((ext_vector_type(8))) _Float16 half8;
typedef __attribute__((ext_vector_type(4))) float f32x4;

// async global->LDS, 16 bytes per lane; lds base must be wave-uniform
__device__ inline void gload16(const void* g, void* l) {
  __builtin_amdgcn_global_load_lds(
      (const __attribute__((address_space(1))) unsigned*)g,
      (__attribute__((address_space(3))) unsigned*)l, 16, 0, 0);
}

__device__ inline float softplus_f(float t) {
  return (t > 20.f) ? t : log1pf(expf(t));
}

// ---------- merged prep: fp32 -> fp16 cvt / hi+lo split ----------
__device__ inline void cvt8_at(const float* __restrict__ in, _Float16* __restrict__ o,
                               int i) {
  f32x4 a = *(const f32x4*)(in + i);
  f32x4 b = *(const f32x4*)(in + i + 4);
  half8 h;
#pragma unroll
  for (int j = 0; j < 4; ++j) h[j] = (_Float16)a[j];
#pragma unroll
  for (int j = 0; j < 4; ++j) h[4 + j] = (_Float16)b[j];
  *(half8*)(o + i) = h;
}
__device__ inline void split8_at(const float* __restrict__ in,
                                 _Float16* __restrict__ hi,
                                 _Float16* __restrict__ lo, int i) {
  f32x4 a = *(const f32x4*)(in + i);
  f32x4 b = *(const f32x4*)(in + i + 4);
  half8 h, l;
#pragma unroll
  for (int j = 0; j < 4; ++j) {
    _Float16 hb = (_Float16)a[j];
    h[j] = hb; l[j] = (_Float16)(a[j] - (float)hb);
  }
#pragma unroll
  for (int j = 0; j < 4; ++j) {
    _Float16 hb = (_Float16)b[j];
    h[4 + j] = hb; l[4 + j] = (_Float16)(b[j] - (float)hb);
  }
  *(half8*)(hi + i) = h;
  *(half8*)(lo + i) = l;
}

__global__ void prep(const float* __restrict__ x, const float* __restrict__ wi,
                     const float* __restrict__ wdt, const float* __restrict__ wo,
                     _Float16* __restrict__ xh,
                     _Float16* __restrict__ wih, _Float16* __restrict__ wil,
                     _Float16* __restrict__ dth, _Float16* __restrict__ dtl,
                     _Float16* __restrict__ oh, _Float16* __restrict__ ol) {
  int blk = blockIdx.x, tid = threadIdx.x;
  if (blk < 1024) {                       // x: 2M elems
    cvt8_at(x, xh, (blk * 256 + tid) * 8);
  } else if (blk < 3072) {                // in_proj_w: 4M
    split8_at(wi, wih, wil, ((blk - 1024) * 256 + tid) * 8);
  } else if (blk < 5120) {                // dt_proj_w: 4M
    split8_at(wdt, dth, dtl, ((blk - 3072) * 256 + tid) * 8);
  } else {                                // out_proj_w: 2M
    split8_at(wo, oh, ol, ((blk - 5120) * 256 + tid) * 8);
  }
}

// ---------- fp16 2-term MFMA GEMM: C[M,N] = A[M,K] * W[N,K]^T ----------
template <int TM, int TN>
__global__ __launch_bounds__(256) void gemm_mfma(
    const _Float16* __restrict__ Ag, const _Float16* __restrict__ Whg,
    const _Float16* __restrict__ Wlg, float* __restrict__ C,
    int M, int N, int K) {
  constexpr int FI = TM / 32, FJ = TN / 32;
  __shared__ _Float16 Ah[TM * BK], Wh[TN * BK], Wl[TN * BK];
  int tid = threadIdx.x, lane = tid & 63, wid = tid >> 6;

  // split-K slice
  int ksl = K / gridDim.z;
  int kBeg = blockIdx.z * ksl, kEnd = kBeg + ksl;
  C += (size_t)blockIdx.z * M * N;

  // XCD-aware swizzle (nwg is a multiple of 8 for all our launches)
  int gx = gridDim.x, nwg = gx * gridDim.y;
  int id = blockIdx.y * gx + blockIdx.x;
  int swz = (id & 7) * (nwg >> 3) + (id >> 3);
  int m0 = (swz / gx) * TM, n0 = (swz % gx) * TN;

  int wm = (wid >> 1) * (TM / 2), wn = (wid & 1) * (TN / 2);
  int fr = lane & 15, fq = lane >> 4;

  f32x4 acc[FI][FJ];
#pragma unroll
  for (int i = 0; i < FI; ++i)
#pragma unroll
    for (int j = 0; j < FJ; ++j) acc[i][j] = (f32x4){0.f, 0.f, 0.f, 0.f};

  for (int k0 = kBeg; k0 < kEnd; k0 += BK) {
#pragma unroll
    for (int q = 0; q < TM / 64; ++q) {
      int i = q * 256 + wid * 64 + lane;
      int row = i >> 2, col = (i & 3) * 8;
      size_t go = (size_t)(m0 + row) * K + k0 + col;
      int lo8 = (q * 256 + wid * 64) * 8;       // wave-uniform LDS elem offset
      gload16(Ag + go, &Ah[lo8]);
    }
#pragma unroll
    for (int q = 0; q < TN / 64; ++q) {
      int i = q * 256 + wid * 64 + lane;
      int row = i >> 2, col = (i & 3) * 8;
      size_t go = (size_t)(n0 + row) * K + k0 + col;
      int lo8 = (q * 256 + wid * 64) * 8;
      gload16(Whg + go, &Wh[lo8]);
      gload16(Wlg + go, &Wl[lo8]);
    }
    __syncthreads();

    half8 ah[FI], wh[FJ], wl[FJ];
#pragma unroll
    for (int f = 0; f < FI; ++f) {
      int ra = (wm + f * 16 + fr) * BK + fq * 8;
      ah[f] = *(const half8*)&Ah[ra];
    }
#pragma unroll
    for (int f = 0; f < FJ; ++f) {
      int rw = (wn + f * 16 + fr) * BK + fq * 8;
      wh[f] = *(const half8*)&Wh[rw];
      wl[f] = *(const half8*)&Wl[rw];
    }
#pragma unroll
    for (int i = 0; i < FI; ++i)
#pragma unroll
      for (int j = 0; j < FJ; ++j) {
        acc[i][j] = __builtin_amdgcn_mfma_f32_16x16x32_f16(ah[i], wh[j], acc[i][j], 0, 0, 0);
        acc[i][j] = __builtin_amdgcn_mfma_f32_16x16x32_f16(ah[i], wl[j], acc[i][j], 0, 0, 0);
      }
    __syncthreads();
  }

#pragma unroll
  for (int i = 0; i < FI; ++i) {
    int m = m0 + wm + i * 16 + fq * 4;
#pragma unroll
    for (int j = 0; j < FJ; ++j) {
      int n = n0 + wn + j * 16 + fr;
#pragma unroll
      for (int r = 0; r < 4; ++r)
        C[(size_t)(m + r) * N + n] = acc[i][j][r];
    }
  }
}

// ---------- split-K reduction (plain add, for out_proj) ----------
__global__ void reduce2(const float* __restrict__ P, float* __restrict__ C, int MN) {
  int i = (blockIdx.x * 256 + threadIdx.x) * 4;
  f32x4 a = *(const f32x4*)(P + i);
  f32x4 b = *(const f32x4*)(P + MN + i);
  *(f32x4*)(C + i) = a + b;
}

// ---------- depthwise conv1d k=3 pad=1 + bias + silu -> fp16 ----------
__global__ void conv_silu(const float* __restrict__ xz, const float* __restrict__ cw,
                          const float* __restrict__ cb,
                          _Float16* __restrict__ xsch) {
  int idx = blockIdx.x * 256 + threadIdx.x;  // over B*L*DI
  int d = idx & (DI - 1);
  int bt = idx >> 11;           // row index (b*L + t)
  int t = bt & (LSEQ - 1);
  const float* base = xz + (size_t)bt * (2 * DI) + d;  // xs part: cols [0,DI)
  float acc = cb[d];
  float w0 = cw[d * 3 + 0], w1 = cw[d * 3 + 1], w2 = cw[d * 3 + 2];
  if (t > 0) acc += base[-(2 * DI)] * w0;
  acc += base[0] * w1;
  if (t < LSEQ - 1) acc += base[2 * DI] * w2;
  float s = acc / (1.f + __expf(-acc));   // silu
  xsch[idx] = (_Float16)s;
}

// ---------- small GEMM: BC[M,32] = xsc[M,DI](fp16) * x_proj_w[32,DI]^T ----------
__global__ void gemm_bc(const _Float16* __restrict__ A, const float* __restrict__ W,
                        float* __restrict__ C) {
  int tid = threadIdx.x;          // 256 threads: 32 n x 8 rows
  int n = tid & 31;
  int r = tid >> 5;
  int m = blockIdx.x * 8 + r;
  const half8* a = (const half8*)(A + (size_t)m * DI);
  const f32x4* w = (const f32x4*)(W + (size_t)n * DI);
  float acc = 0.f;
#pragma unroll 2
  for (int k = 0; k < DI / 8; ++k) {
    half8 av = a[k];
    f32x4 w0 = w[2 * k], w1 = w[2 * k + 1];
    acc += (float)av[0] * w0[0] + (float)av[1] * w0[1] +
           (float)av[2] * w0[2] + (float)av[3] * w0[3] +
           (float)av[4] * w1[0] + (float)av[5] * w1[1] +
           (float)av[6] * w1[2] + (float)av[7] * w1[3];
  }
  C[m * 32 + n] = acc;
}

// ---------- chunked parallel scan ----------
// Phase A: per (b,d,chunk): local scan h0=0; delta computed inline from the
// two split-K partials + bias (softplus). Writes chunk summary hloc, dsum.
__global__ void scan_phaseA(const float* __restrict__ dtP,
                            const _Float16* __restrict__ xsch,
                            const float* __restrict__ bc,
                            const float* __restrict__ A_log,
                            const float* __restrict__ dtb,
                            float* __restrict__ hloc,
                            float* __restrict__ dsum) {
  int tid = threadIdx.x;
  int d = blockIdx.x * 256 + tid;
  int c = blockIdx.y;
  int b = blockIdx.z;
  const float* dtP1 = dtP + (size_t)MROWS * DI;
  float bias = dtb[d];
  float Av[DS];
#pragma unroll
  for (int n = 0; n < DS; n += 4) {
    float4 v = *(const float4*)(A_log + d * DS + n);
    Av[n] = -__expf(v.x); Av[n+1] = -__expf(v.y);
    Av[n+2] = -__expf(v.z); Av[n+3] = -__expf(v.w);
  }
  float h[DS] = {};
  float sd = 0.f;
  size_t row = (size_t)b * LSEQ + (size_t)c * CLEN;
  for (int t = 0; t < CLEN; ++t, ++row) {
    float dlt = softplus_f(dtP[row * DI + d] + dtP1[row * DI + d] + bias);
    float xv  = (float)xsch[row * DI + d];
    float dx = dlt * xv;
    sd += dlt;
#pragma unroll
    for (int n = 0; n < DS; ++n) {
      float Bn = bc[row * 32 + n];
      float dA = __expf(dlt * Av[n]);
      h[n] = dA * h[n] + dx * Bn;
    }
  }
  size_t o = ((size_t)(b * NC + c) * DI + d) * DS;
#pragma unroll
  for (int n = 0; n < DS; n += 4)
    *(float4*)(hloc + o + n) = make_float4(h[n], h[n+1], h[n+2], h[n+3]);
  dsum[(b * NC + c) * DI + d] = sd;
}

// Phase B: wave-segmented affine scan over chunks. One wave per (b,d);
// lane = (seg, n): seg in [0,4) handles 16 chunks; 2-step shuffle compose.
__global__ void scan_phaseB(const float* __restrict__ hloc,
                            const float* __restrict__ dsum,
                            const float* __restrict__ A_log,
                            float* __restrict__ hin) {
  int tid = threadIdx.x, lane = tid & 63, wid = tid >> 6;
  int n = lane & 15, seg = lane >> 4;
  int dg = blockIdx.x * 4 + wid;          // over B*DI
  int b = dg >> 11, d = dg & (DI - 1);
  float Av = -__expf(A_log[d * DS + n]);
  float p[CLEN], q[CLEN];
  float P = 1.f, Q = 0.f;
  int c0 = seg * 16;
#pragma unroll
  for (int i = 0; i < 16; ++i) {
    size_t cb = (size_t)(b * NC + c0 + i) * DI + d;
    float pi = __expf(Av * dsum[cb]);
    float qi = hloc[cb * DS + n];
    p[i] = pi; q[i] = qi;
    Q = pi * Q + qi;
    P *= pi;
  }
  // Hillis-Steele inclusive scan across the 4 segments (affine compose)
#pragma unroll
  for (int off = 16; off <= 32; off <<= 1) {
    float Pp = __shfl_up(P, off, 64);
    float Qp = __shfl_up(Q, off, 64);
    if (lane >= off) { Q = P * Qp + Q; P = P * Pp; }
  }
  float h = __shfl_up(Q, 16, 64);   // exclusive prefix (h0 = 0)
  if (seg == 0) h = 0.f;
#pragma unroll
  for (int i = 0; i < 16; ++i) {
    size_t cb = (size_t)(b * NC + c0 + i) * DI + d;
    hin[cb * DS + n] = h;
    h = p[i] * h + q[i];
  }
}

// Phase C: scan within chunk seeded with hin; hidden written coalesced via LDS;
// fused y = (sum h*C + x*D) * silu(z) emitted as fp16 for the out_proj GEMM.
#define HS_STRIDE 20   // floats; 80B: 16B-aligned, breaks 64B bank pattern
__global__ void scan_phaseC(const float* __restrict__ dtP,
                            const _Float16* __restrict__ xsch,
                            const float* __restrict__ bc,
                            const float* __restrict__ xz,
                            const float* __restrict__ A_log,
                            const float* __restrict__ Dv,
                            const float* __restrict__ dtb,
                            const float* __restrict__ hin,
                            float* __restrict__ hidden,
                            _Float16* __restrict__ yh) {
  __shared__ float hs[256 * HS_STRIDE];
  int tid = threadIdx.x;
  int d0 = blockIdx.x * 256;
  int d = d0 + tid;
  int c = blockIdx.y;
  int b = blockIdx.z;
  const float* dtP1 = dtP + (size_t)MROWS * DI;
  float bias = dtb[d];
  float Av[DS];
#pragma unroll
  for (int n = 0; n < DS; n += 4) {
    float4 v = *(const float4*)(A_log + d * DS + n);
    Av[n] = -__expf(v.x); Av[n+1] = -__expf(v.y);
    Av[n+2] = -__expf(v.z); Av[n+3] = -__expf(v.w);
  }
  float Dd = Dv[d];
  float h[DS];
  size_t so = ((size_t)(b * NC + c) * DI + d) * DS;
#pragma unroll
  for (int n = 0; n < DS; n += 4) {
    float4 v = *(const float4*)(hin + so + n);
    h[n] = v.x; h[n+1] = v.y; h[n+2] = v.z; h[n+3] = v.w;
  }
  size_t row = (size_t)b * LSEQ + (size_t)c * CLEN;
  for (int t = 0; t < CLEN; ++t, ++row) {
    float dlt = softplus_f(dtP[row * DI + d] + dtP1[row * DI + d] + bias);
    float xv  = (float)xsch[row * DI + d];
    float dx = dlt * xv;
    float y = 0.f;
#pragma unroll
    for (int n = 0; n < DS; ++n) {
      float Bn = bc[row * 32 + n];
      float Cn = bc[row * 32 + 16 + n];
      float dA = __expf(dlt * Av[n]);
      h[n] = dA * h[n] + dx * Bn;
      y += h[n] * Cn;
    }
    // stage h into LDS, then cooperatively write 16KB contiguous
#pragma unroll
    for (int n = 0; n < DS; n += 4)
      *(float4*)&hs[tid * HS_STRIDE + n] = make_float4(h[n], h[n+1], h[n+2], h[n+3]);
    __syncthreads();
    size_t basef = ((size_t)row * DI + d0) * DS;   // 4096 floats for this block
#pragma unroll
    for (int k = 0; k < 4; ++k) {
      int f4 = tid + 256 * k;            // float4 index within slab
      int owner = f4 >> 2;
      int elem = (f4 & 3) * 4;
      float4 v = *(const float4*)&hs[owner * HS_STRIDE + elem];
      *(float4*)&hidden[basef + (size_t)f4 * 4] = v;
    }
    __syncthreads();
    float zv = xz[row * (2 * DI) + DI + d];
    float sz = zv / (1.f + __expf(-zv));
    yh[row * DI + d] = (_Float16)((y + xv * Dd) * sz);
  }
}

extern "C" void kernel_launch(void* const* d_in, const int* in_sizes, int n_in,
                              void* d_out, int out_size, void* d_ws, size_t ws_size,
                              hipStream_t stream) {
  const float* x         = (const float*)d_in[0];
  const float* in_proj_w = (const float*)d_in[1];
  const float* conv_w    = (const float*)d_in[2];
  const float* conv_b    = (const float*)d_in[3];
  const float* x_proj_w  = (const float*)d_in[4];
  const float* dt_proj_w = (const float*)d_in[5];
  const float* dt_proj_b = (const float*)d_in[6];
  const float* out_proj_w= (const float*)d_in[7];
  const float* A_log     = (const float*)d_in[8];
  const float* Dvec      = (const float*)d_in[9];

  float* out    = (float*)d_out;                            // (B,L,DM)
  float* hidden = (float*)d_out + (size_t)BSZ * LSEQ * DM;  // (B,L,DI,DS)

  float* ws  = (float*)d_ws;
  float* xz    = ws;                                   // (M, 2*DI)  8M floats
  float* bcbuf = xz  + (size_t)MROWS * 2 * DI;         // (M, 32)
  float* hloc  = bcbuf + (size_t)MROWS * 32;           // (B,NC,DI,DS) 4M
  float* hin   = hloc + (size_t)BSZ * NC * DI * DS;    // (B,NC,DI,DS) 4M
  float* dsum  = hin  + (size_t)BSZ * NC * DI * DS;    // (B,NC,DI)  256K
  float* dtP   = dsum + (size_t)BSZ * NC * DI;         // 2x(M,DI)   8M
  float* outP  = dtP + (size_t)2 * MROWS * DI;         // 2x(M,DM)   4M

  _Float16* hp = (_Float16*)(outP + (size_t)2 * MROWS * DM);
  _Float16* xh   = hp;                                 // (M,DM)    2M
  _Float16* wih  = xh + (size_t)MROWS * DM;            // (2DI,DM)  4M
  _Float16* wil  = wih + (size_t)2 * DI * DM;
  _Float16* dth  = wil + (size_t)2 * DI * DM;          // (DI,DI)   4M
  _Float16* dtl  = dth + (size_t)DI * DI;
  _Float16* oh   = dtl + (size_t)DI * DI;              // (DM,DI)   2M
  _Float16* ol   = oh + (size_t)DM * DI;
  _Float16* xsch = ol + (size_t)DM * DI;               // (M,DI)    4M
  _Float16* yh   = xsch + (size_t)MROWS * DI;          // (M,DI)    4M

  dim3 blk(256);

  // 0) merged prep: cvt x, split the three weight matrices
  prep<<<dim3(6144), blk, 0, stream>>>(x, in_proj_w, dt_proj_w, out_proj_w,
                                       xh, wih, wil, dth, dtl, oh, ol);

  // 1) xz = x @ in_proj_w^T   (M=2048, N=4096, K=1024); 512 blocks
  gemm_mfma<128, 128><<<dim3((2 * DI) / 128, MROWS / 128, 1), blk, 0, stream>>>(
      xh, wih, wil, xz, MROWS, 2 * DI, DM);

  // 2) depthwise conv + silu -> xsch (fp16)
  conv_silu<<<dim3((BSZ * LSEQ * DI) / 256), blk, 0, stream>>>(
      xz, conv_w, conv_b, xsch);

  // 3) dt partials (split-K=2; 512 blocks); softplus fused into scan phases
  gemm_mfma<128, 128><<<dim3(DI / 128, MROWS / 128, 2), blk, 0, stream>>>(
      xsch, dth, dtl, dtP, MROWS, DI, DI);

  // 4) BC = xsc @ x_proj_w^T   (N=32)
  gemm_bc<<<dim3(MROWS / 8), blk, 0, stream>>>(xsch, x_proj_w, bcbuf);

  // 5) chunked parallel scan -> hidden, y (fp16)
  scan_phaseA<<<dim3(DI / 256, NC, BSZ), blk, 0, stream>>>(
      dtP, xsch, bcbuf, A_log, dt_proj_b, hloc, dsum);
  scan_phaseB<<<dim3((BSZ * DI) / 4), blk, 0, stream>>>(
      hloc, dsum, A_log, hin);
  scan_phaseC<<<dim3(DI / 256, NC, BSZ), blk, 0, stream>>>(
      dtP, xsch, bcbuf, xz, A_log, Dvec, dt_proj_b, hin, hidden, yh);

  // 6) out partials (split-K=2, TM=64; 512 blocks), then out = P0+P1
  gemm_mfma<64, 128><<<dim3(DM / 128, MROWS / 64, 2), blk, 0, stream>>>(
      yh, oh, ol, outP, MROWS, DM, DI);
  reduce2<<<dim3((MROWS * DM) / 1024), blk, 0, stream>>>(
      outP, out, MROWS * DM);
}